// Round 7
// baseline (420.799 us; speedup 1.0000x reference)
//
#include <hip/hip_runtime.h>
#include <math.h>

#define C_   256
#define CQ_  32
#define H_   128
#define W_   128
#define HW_  (H_ * W_)
#define OC_  320   // 0..31 q, 32..63 k, 64..319 v

typedef __attribute__((ext_vector_type(8))) short  s8v;   // 8 bf16 (A/B frag)
typedef __attribute__((ext_vector_type(4))) float  f4v;   // 4 fp32 (C/D frag)
typedef __attribute__((ext_vector_type(8))) unsigned short u8v;
typedef __attribute__((ext_vector_type(4))) unsigned short u4v;

__device__ inline unsigned short f2bf(float f) {
    unsigned int u = __float_as_uint(f);
    unsigned int r = (u + 0x7fffu + ((u >> 16) & 1u)) >> 16;
    return (unsigned short)r;
}
__device__ inline float bfu(unsigned short u) {
    return __uint_as_float((unsigned int)u << 16);
}

// convert ushort8 (bf16) -> 8 floats written to dst (16B-aligned)
__device__ inline void cvt8(const u8v u, float* dst) {
    float4 lo, hi;
    lo.x = bfu(u[0]); lo.y = bfu(u[1]); lo.z = bfu(u[2]); lo.w = bfu(u[3]);
    hi.x = bfu(u[4]); hi.y = bfu(u[5]); hi.z = bfu(u[6]); hi.w = bfu(u[7]);
    *(float4*)dst = lo;
    *(float4*)(dst + 4) = hi;
}

// ------------------------------------------------ K0: W -> bf16 (320x256)
__global__ __launch_bounds__(256) void k_wconv(
    const float* __restrict__ wq, const float* __restrict__ wk,
    const float* __restrict__ wv, unsigned short* __restrict__ Wb)
{
    int idx4 = blockIdx.x * 256 + threadIdx.x;     // 20480 total
    int e = idx4 * 4;
    int oc = e >> 8, k = e & 255;
    const float* src;
    if (oc < 32)      src = wq + (size_t)oc * C_ + k;
    else if (oc < 64) src = wk + (size_t)(oc - 32) * C_ + k;
    else              src = wv + (size_t)(oc - 64) * C_ + k;
    float4 v = *(const float4*)src;
    u4v o;
    o[0] = f2bf(v.x); o[1] = f2bf(v.y); o[2] = f2bf(v.z); o[3] = f2bf(v.w);
    *(u4v*)(Wb + e) = o;
}

// ---------------------------------------------------------- K1: QKV MFMA GEMM
// qkv[bb][oc][n] = W[oc,:] @ x[b0+bb][:,n] + bias[oc]   (bf16 out)
// grid (HW/128, 5, nb), block 256 (4 waves); wave tile 64oc x 32n
// v2: W frags in registers (whole K); X staged as k-pair-packed bf16 dwords,
//     double-buffered, 1 barrier per K-64 step, async-stage split.
__global__ __launch_bounds__(256) void k_qkv(
    const float* __restrict__ x, const unsigned short* __restrict__ Wb,
    const float* __restrict__ bq, const float* __restrict__ bk,
    const float* __restrict__ bv,
    unsigned short* __restrict__ qkv, int b0)
{
    __shared__ __align__(16) unsigned int Xp[2][32 * 132];  // 33.8 KB total
    const int t = threadIdx.x;
    const int lane = t & 63;
    const int wave = t >> 6;
    const int n0 = blockIdx.x * 128;
    const int ocblk = blockIdx.y * 64;
    const int bb = blockIdx.z;
    const float* xb = x + (size_t)(b0 + bb) * C_ * HW_;

    const int lg = lane >> 4;      // 0..3
    const int ll = lane & 15;      // 0..15
    const int n_w = wave * 32;

    // A fragments (W) -> registers, whole K = 256
    s8v afr[8][4];
    #pragma unroll
    for (int mr = 0; mr < 4; ++mr)
        #pragma unroll
        for (int ks = 0; ks < 8; ++ks)
            afr[ks][mr] = *(const s8v*)(
                Wb + (size_t)(ocblk + mr * 16 + ll) * C_ + ks * 32 + lg * 8);

    f4v acc[4][2];
    #pragma unroll
    for (int mr = 0; mr < 4; ++mr)
        #pragma unroll
        for (int nr = 0; nr < 2; ++nr)
            acc[mr][nr] = (f4v){0.f, 0.f, 0.f, 0.f};

    const int kp8 = t >> 5;          // 0..7
    const int n4  = (t & 31) * 4;    // 0..124
    float4 ra[4], rb[4];

    // issue loads for kc = 0
    #pragma unroll
    for (int p = 0; p < 4; ++p) {
        int krow = (p * 8 + kp8) * 2;
        ra[p] = *(const float4*)(xb + (size_t)krow * HW_ + n0 + n4);
        rb[p] = *(const float4*)(xb + (size_t)(krow + 1) * HW_ + n0 + n4);
    }

    #pragma unroll
    for (int kc = 0; kc < 4; ++kc) {
        unsigned int* XB = Xp[kc & 1];
        // pack fp32 pair -> bf16 dword (round half-up), write b128
        #pragma unroll
        for (int p = 0; p < 4; ++p) {
            uint4 d;
            const float* af  = (const float*)&ra[p];
            const float* bf_ = (const float*)&rb[p];
            #pragma unroll
            for (int i = 0; i < 4; ++i) {
                unsigned int lo = (__float_as_uint(af[i])  + 0x8000u) >> 16;
                unsigned int hi = (__float_as_uint(bf_[i]) + 0x8000u) & 0xffff0000u;
                ((unsigned int*)&d)[i] = hi | lo;
            }
            *(uint4*)&XB[(p * 8 + kp8) * 132 + n4] = d;
        }
        // issue next chunk's global loads (overlap with compute below)
        if (kc < 3) {
            #pragma unroll
            for (int p = 0; p < 4; ++p) {
                int krow = (kc + 1) * 64 + (p * 8 + kp8) * 2;
                ra[p] = *(const float4*)(xb + (size_t)krow * HW_ + n0 + n4);
                rb[p] = *(const float4*)(xb + (size_t)(krow + 1) * HW_ + n0 + n4);
            }
        }
        __syncthreads();
        #pragma unroll
        for (int ks = 0; ks < 2; ++ks) {
            #pragma unroll
            for (int nr = 0; nr < 2; ++nr) {
                int4 bd;
                #pragma unroll
                for (int e2 = 0; e2 < 4; ++e2)
                    ((int*)&bd)[e2] =
                        XB[(ks * 16 + lg * 4 + e2) * 132 + n_w + nr * 16 + ll];
                s8v bfr = *(s8v*)&bd;
                #pragma unroll
                for (int mr = 0; mr < 4; ++mr)
                    acc[mr][nr] = __builtin_amdgcn_mfma_f32_16x16x32_bf16(
                        afr[kc * 2 + ks][mr], bfr, acc[mr][nr], 0, 0, 0);
            }
        }
    }

    #pragma unroll
    for (int mr = 0; mr < 4; ++mr) {
        float bias[4];
        #pragma unroll
        for (int r = 0; r < 4; ++r) {
            int oc = ocblk + mr * 16 + lg * 4 + r;
            if (oc < 32)      bias[r] = bq[oc];
            else if (oc < 64) bias[r] = bk[oc - 32];
            else              bias[r] = bv[oc - 64];
        }
        #pragma unroll
        for (int nr = 0; nr < 2; ++nr) {
            int n = n0 + n_w + nr * 16 + ll;
            #pragma unroll
            for (int r = 0; r < 4; ++r) {
                int oc = ocblk + mr * 16 + lg * 4 + r;
                qkv[((size_t)bb * OC_ + oc) * HW_ + n] = f2bf(acc[mr][nr][r] + bias[r]);
            }
        }
    }
}

// ------------------------------------------------- K1b: transpose to (b,w,oc,h)
__global__ __launch_bounds__(256) void k_transpose_qkv(
    const unsigned short* __restrict__ qkv, unsigned short* __restrict__ qkv_t)
{
    __shared__ unsigned short tile[32][34];
    const int bb = blockIdx.z;
    const int oc = blockIdx.y;
    const int th = (blockIdx.x & 3) * 32;
    const int tw = (blockIdx.x >> 2) * 32;
    const unsigned short* src = qkv + ((size_t)bb * OC_ + oc) * HW_;
    #pragma unroll
    for (int r = 0; r < 4; ++r) {
        int h = threadIdx.y * 4 + r;
        tile[h][threadIdx.x] = src[(size_t)(th + h) * W_ + tw + threadIdx.x];
    }
    __syncthreads();
    unsigned short* dst = qkv_t + (size_t)bb * W_ * OC_ * H_;
    #pragma unroll
    for (int r = 0; r < 4; ++r) {
        int wl = threadIdx.y * 4 + r;
        dst[((size_t)(tw + wl) * OC_ + oc) * H_ + th + threadIdx.x] = tile[threadIdx.x][wl];
    }
}

// ----------------------------------------------- K2a: column (e_h) softmax stats
__global__ __launch_bounds__(128) void k_stats_h(
    const unsigned short* __restrict__ qkv_t,
    float* __restrict__ mh, float* __restrict__ sh)
{
    __shared__ __align__(16) float Qc[CQ_][H_];
    const int t = threadIdx.x;            // i
    const int beta = blockIdx.x;
    const int bb = blockIdx.y;
    const unsigned short* base = qkv_t + ((size_t)bb * W_ + beta) * OC_ * H_;
    for (int f = t * 8; f < CQ_ * H_; f += 1024)
        cvt8(*(const u8v*)(base + f), &Qc[0][f]);
    float kreg[CQ_];
    #pragma unroll
    for (int c = 0; c < CQ_; ++c) kreg[c] = bfu(base[(size_t)(32 + c) * H_ + t]);
    __syncthreads();
    float m = -INFINITY, s = 0.f;
    for (int jq = 0; jq < 32; ++jq) {
        float e[4] = {0.f, 0.f, 0.f, 0.f};
        #pragma unroll
        for (int c = 0; c < CQ_; ++c) {
            float4 q4 = *(const float4*)&Qc[c][jq * 4];
            e[0] += kreg[c] * q4.x; e[1] += kreg[c] * q4.y;
            e[2] += kreg[c] * q4.z; e[3] += kreg[c] * q4.w;
        }
        int jb = jq * 4;
        if (t >= jb && t < jb + 4) e[t - jb] = -INFINITY;  // diag mask
        float me = fmaxf(fmaxf(e[0], e[1]), fmaxf(e[2], e[3]));
        float mn = fmaxf(m, me);
        s = s * __expf(m - mn) + __expf(e[0] - mn) + __expf(e[1] - mn)
                               + __expf(e[2] - mn) + __expf(e[3] - mn);
        m = mn;
    }
    mh[((size_t)bb * H_ + t) * W_ + beta] = m;
    sh[((size_t)bb * H_ + t) * W_ + beta] = s;
}

// -------------------------------------------------- K2b: row (e_w) softmax stats
__global__ __launch_bounds__(128) void k_stats_w(
    const unsigned short* __restrict__ qkv,
    float* __restrict__ mw, float* __restrict__ sw)
{
    __shared__ __align__(16) float Qr[CQ_][W_];
    const int t = threadIdx.x;            // beta (key col)
    const int alpha = blockIdx.x;
    const int bb = blockIdx.y;
    const unsigned short* base = qkv + (size_t)bb * OC_ * HW_ + (size_t)alpha * W_;
    for (int f = t * 8; f < CQ_ * W_; f += 1024) {
        int c = f >> 7, w = f & 127;
        cvt8(*(const u8v*)(base + (size_t)c * HW_ + w), &Qr[c][w]);
    }
    float kreg[CQ_];
    #pragma unroll
    for (int c = 0; c < CQ_; ++c) kreg[c] = bfu(base[(size_t)(32 + c) * HW_ + t]);
    __syncthreads();
    float m = -INFINITY, s = 0.f;
    for (int jq = 0; jq < 32; ++jq) {
        float e[4] = {0.f, 0.f, 0.f, 0.f};
        #pragma unroll
        for (int c = 0; c < CQ_; ++c) {
            float4 q4 = *(const float4*)&Qr[c][jq * 4];
            e[0] += kreg[c] * q4.x; e[1] += kreg[c] * q4.y;
            e[2] += kreg[c] * q4.z; e[3] += kreg[c] * q4.w;
        }
        float me = fmaxf(fmaxf(e[0], e[1]), fmaxf(e[2], e[3]));
        float mn = fmaxf(m, me);
        s = s * __expf(m - mn) + __expf(e[0] - mn) + __expf(e[1] - mn)
                               + __expf(e[2] - mn) + __expf(e[3] - mn);
        m = mn;
    }
    mw[((size_t)bb * H_ + alpha) * W_ + t] = m;
    sw[((size_t)bb * H_ + alpha) * W_ + t] = s;
}

// ------------------------------- K2c: combine stats -> m_comb, d_inv (+transposed)
// idx = (b*H + p)*W + q  (key position p=row, q=col)
__global__ __launch_bounds__(256) void k_prep(
    const float* __restrict__ mh, const float* __restrict__ sh,
    const float* __restrict__ mw, const float* __restrict__ sw,
    float* __restrict__ mc, float* __restrict__ dv,
    float* __restrict__ mct, float* __restrict__ dvt, int n)
{
    int idx = blockIdx.x * 256 + threadIdx.x;
    if (idx >= n) return;
    float m1 = mh[idx], s1 = sh[idx], m2 = mw[idx], s2 = sw[idx];
    float m = fmaxf(m1, m2);
    float d = 1.f / (s1 * __expf(m1 - m) + s2 * __expf(m2 - m));
    mc[idx] = m; dv[idx] = d;
    int q = idx & (W_ - 1);
    int p = (idx >> 7) & (H_ - 1);
    int b = idx >> 14;
    size_t tid = ((size_t)b * W_ + q) * H_ + p;
    mct[tid] = m; dvt[tid] = d;
}

// -------------------------------------------------------------- K3: out_h (MFMA)
// per (b, beta): oh_t[b][beta][c][j] = sum_i V(c,i) P(i,j)   (bf16 out)
// grid (W, nb), block 256 (4 waves)
__global__ __launch_bounds__(256) void k_outh(
    const unsigned short* __restrict__ qkv_t,
    const float* __restrict__ mct, const float* __restrict__ dvt,
    unsigned short* __restrict__ oh_t)
{
    __shared__ __align__(16) unsigned short Pt[128 * 128];   // swizzled, 32 KB
    __shared__ __align__(16) unsigned char  Ubuf[32 * 132 * 4]; // Qf fp32 | V chunk
    __shared__ float mloc[128], dloc[128];
    float* Qf = (float*)Ubuf;                    // [32][132]
    unsigned short* Vl = (unsigned short*)Ubuf;  // [64][128] swizzled

    const int t = threadIdx.x;
    const int beta = blockIdx.x;
    const int bb = blockIdx.y;
    const unsigned short* base = qkv_t + ((size_t)bb * W_ + beta) * OC_ * H_;

    if (t < 128) {
        size_t sidx = ((size_t)bb * W_ + beta) * H_ + t;
        mloc[t] = mct[sidx];
        dloc[t] = dvt[sidx];
    }
    // stage Q (32 x 128) fp32
    for (int f = t * 8; f < CQ_ * H_; f += 2048) {
        int c = f >> 7, j = f & 127;
        cvt8(*(const u8v*)(base + f), &Qf[c * 132 + j]);
    }
    // K column i in registers
    const int i = t & 127;
    const int jg = t >> 7;
    float kreg[CQ_];
    #pragma unroll
    for (int c = 0; c < CQ_; ++c) kreg[c] = bfu(base[(size_t)(32 + c) * H_ + i]);
    __syncthreads();

    const float m = mloc[i], dv = dloc[i];
    // e + softmax -> Pt[j][i] (bf16, XOR-swizzled)
    for (int jq = 0; jq < 16; ++jq) {
        int j = jg * 64 + jq * 4;
        float e[4] = {0.f, 0.f, 0.f, 0.f};
        #pragma unroll
        for (int c = 0; c < CQ_; ++c) {
            float4 q4 = *(const float4*)&Qf[c * 132 + j];
            e[0] += kreg[c] * q4.x; e[1] += kreg[c] * q4.y;
            e[2] += kreg[c] * q4.z; e[3] += kreg[c] * q4.w;
        }
        #pragma unroll
        for (int u = 0; u < 4; ++u) {
            int jj = j + u;
            float p = (jj == i) ? 0.f : __expf(e[u] - m) * dv;
            Pt[(jj * 128 + i) ^ ((jj & 7) << 3)] = f2bf(p);
        }
    }

    const int lane = t & 63;
    const int wv = t >> 6;
    const int lg = lane >> 4;
    const int ll = lane & 15;
    unsigned short* outbase = oh_t + ((size_t)bb * W_ + beta) * C_ * H_;

    for (int ch = 0; ch < 4; ++ch) {
        __syncthreads();
        // stage V chunk: rows c in [ch*64, ch*64+64)
        const unsigned short* vsrc = base + (size_t)(64 + ch * 64) * H_;
        #pragma unroll
        for (int f = t; f < 1024; f += 256) {
            int c = f >> 4, i0 = (f & 15) * 8;
            u8v v = *(const u8v*)(vsrc + (size_t)c * H_ + i0);
            *(u8v*)&Vl[(c * 128 + i0) ^ ((c & 7) << 3)] = v;
        }
        __syncthreads();

        f4v acc[8];
        #pragma unroll
        for (int nt = 0; nt < 8; ++nt) acc[nt] = (f4v){0.f, 0.f, 0.f, 0.f};

        #pragma unroll
        for (int kk = 0; kk < 4; ++kk) {
            int crow = wv * 16 + ll;
            s8v afr = *(const s8v*)&Vl[(crow * 128 + kk * 32 + lg * 8) ^ ((crow & 7) << 3)];
            #pragma unroll
            for (int nt = 0; nt < 8; ++nt) {
                int j = nt * 16 + ll;
                s8v bfr = *(const s8v*)&Pt[(j * 128 + kk * 32 + lg * 8) ^ ((j & 7) << 3)];
                acc[nt] = __builtin_amdgcn_mfma_f32_16x16x32_bf16(afr, bfr, acc[nt], 0, 0, 0);
            }
        }
        // store: c = ch*64 + wv*16 + lg*4 + r, j = nt*16 + ll
        #pragma unroll
        for (int nt = 0; nt < 8; ++nt) {
            int j = nt * 16 + ll;
            #pragma unroll
            for (int r = 0; r < 4; ++r) {
                int c = ch * 64 + wv * 16 + lg * 4 + r;
                outbase[(size_t)c * H_ + j] = f2bf(acc[nt][r]);
            }
        }
    }
}

// -------------------------------------------------------------- K4: out_w (MFMA)
// per (b, alpha): ow[b][c][alpha][j] = sum_i V(c,i) Pw(i,j)   (bf16 out)
__global__ __launch_bounds__(256) void k_outw(
    const unsigned short* __restrict__ qkv,
    const float* __restrict__ mc, const float* __restrict__ dv_,
    unsigned short* __restrict__ ow)
{
    __shared__ __align__(16) unsigned short Pt[128 * 128];
    __shared__ __align__(16) unsigned char  Ubuf[32 * 132 * 4];
    __shared__ float mloc[128], dloc[128];
    float* Qf = (float*)Ubuf;
    unsigned short* Vl = (unsigned short*)Ubuf;

    const int t = threadIdx.x;
    const int alpha = blockIdx.x;
    const int bb = blockIdx.y;
    const unsigned short* base = qkv + (size_t)bb * OC_ * HW_ + (size_t)alpha * W_;

    if (t < 128) {
        size_t sidx = ((size_t)bb * H_ + alpha) * W_ + t;
        mloc[t] = mc[sidx];
        dloc[t] = dv_[sidx];
    }
    for (int f = t * 8; f < CQ_ * W_; f += 2048) {
        int c = f >> 7, j = f & 127;
        cvt8(*(const u8v*)(base + (size_t)c * HW_ + j), &Qf[c * 132 + j]);
    }
    const int i = t & 127;
    const int jg = t >> 7;
    float kreg[CQ_];
    #pragma unroll
    for (int c = 0; c < CQ_; ++c) kreg[c] = bfu(base[(size_t)(32 + c) * HW_ + i]);
    __syncthreads();

    const float m = mloc[i], dv = dloc[i];
    for (int jq = 0; jq < 16; ++jq) {
        int j = jg * 64 + jq * 4;
        float e[4] = {0.f, 0.f, 0.f, 0.f};
        #pragma unroll
        for (int c = 0; c < CQ_; ++c) {
            float4 q4 = *(const float4*)&Qf[c * 132 + j];
            e[0] += kreg[c] * q4.x; e[1] += kreg[c] * q4.y;
            e[2] += kreg[c] * q4.z; e[3] += kreg[c] * q4.w;
        }
        #pragma unroll
        for (int u = 0; u < 4; ++u) {
            int jj = j + u;
            float p = __expf(e[u] - m) * dv;     // no diag mask in e_w
            Pt[(jj * 128 + i) ^ ((jj & 7) << 3)] = f2bf(p);
        }
    }

    const int lane = t & 63;
    const int wv = t >> 6;
    const int lg = lane >> 4;
    const int ll = lane & 15;
    unsigned short* obase = ow + (size_t)bb * C_ * HW_ + (size_t)alpha * W_;

    for (int ch = 0; ch < 4; ++ch) {
        __syncthreads();
        const unsigned short* vsrc = base + (size_t)(64 + ch * 64) * HW_;
        #pragma unroll
        for (int f = t; f < 1024; f += 256) {
            int c = f >> 4, i0 = (f & 15) * 8;
            u8v v = *(const u8v*)(vsrc + (size_t)c * HW_ + i0);
            *(u8v*)&Vl[(c * 128 + i0) ^ ((c & 7) << 3)] = v;
        }
        __syncthreads();

        f4v acc[8];
        #pragma unroll
        for (int nt = 0; nt < 8; ++nt) acc[nt] = (f4v){0.f, 0.f, 0.f, 0.f};

        #pragma unroll
        for (int kk = 0; kk < 4; ++kk) {
            int crow = wv * 16 + ll;
            s8v afr = *(const s8v*)&Vl[(crow * 128 + kk * 32 + lg * 8) ^ ((crow & 7) << 3)];
            #pragma unroll
            for (int nt = 0; nt < 8; ++nt) {
                int j = nt * 16 + ll;
                s8v bfr = *(const s8v*)&Pt[(j * 128 + kk * 32 + lg * 8) ^ ((j & 7) << 3)];
                acc[nt] = __builtin_amdgcn_mfma_f32_16x16x32_bf16(afr, bfr, acc[nt], 0, 0, 0);
            }
        }
        #pragma unroll
        for (int nt = 0; nt < 8; ++nt) {
            int j = nt * 16 + ll;
            #pragma unroll
            for (int r = 0; r < 4; ++r) {
                int c = ch * 64 + wv * 16 + lg * 4 + r;
                obase[(size_t)c * HW_ + j] = f2bf(acc[nt][r]);
            }
        }
    }
}

// ------------------------------- K5: out = x + gamma*(ow + oh^T)  (fused epilogue)
__global__ __launch_bounds__(256) void k_combine(
    const unsigned short* __restrict__ oh_t, const unsigned short* __restrict__ ow,
    const float* __restrict__ x, const float* __restrict__ gamma_p,
    float* __restrict__ out, int b0)
{
    __shared__ float tile[32][33];
    const int bb = blockIdx.z;
    const int c = blockIdx.y;
    const int th = (blockIdx.x & 3) * 32;
    const int tw = (blockIdx.x >> 2) * 32;
    const float gamma = gamma_p[0];
    const unsigned short* src = oh_t + (size_t)bb * W_ * C_ * H_;
    #pragma unroll
    for (int r = 0; r < 4; ++r) {
        int wl = threadIdx.y * 4 + r;
        tile[wl][threadIdx.x] =
            bfu(src[((size_t)(tw + wl) * C_ + c) * H_ + th + threadIdx.x]);
    }
    __syncthreads();
    const size_t pbase = ((size_t)bb * C_ + c) * HW_;
    const size_t gbase = ((size_t)(b0 + bb) * C_ + c) * HW_;
    #pragma unroll
    for (int r = 0; r < 4; ++r) {
        int hl = threadIdx.y * 4 + r;
        size_t idx = (size_t)(th + hl) * W_ + tw + threadIdx.x;
        float owv = bfu(ow[pbase + idx]);
        out[gbase + idx] = x[gbase + idx] + gamma * (owv + tile[threadIdx.x][hl]);
    }
}

// ------------------------------------------------------------------- launcher
extern "C" void kernel_launch(void* const* d_in, const int* in_sizes, int n_in,
                              void* d_out, int out_size, void* d_ws, size_t ws_size,
                              hipStream_t stream)
{
    (void)in_sizes; (void)n_in; (void)out_size;
    const float* x  = (const float*)d_in[0];
    const float* wq = (const float*)d_in[1];
    const float* bq = (const float*)d_in[2];
    const float* wk = (const float*)d_in[3];
    const float* bk = (const float*)d_in[4];
    const float* wv = (const float*)d_in[5];
    const float* bv = (const float*)d_in[6];
    const float* gm = (const float*)d_in[7];
    float* out = (float*)d_out;

    const size_t e_qkv  = (size_t)OC_ * HW_;   // bf16 elements
    const size_t e_out  = (size_t)C_ * HW_;    // bf16 elements
    const size_t e_stat = (size_t)HW_;         // fp32 elements
    const size_t perb_bytes = (e_qkv * 2 + e_out * 2) * 2 + e_stat * 8 * 4;
    const size_t wb_bytes = (size_t)OC_ * C_ * 2;
    int nbcap = (int)((ws_size - wb_bytes) / perb_bytes);
    if (nbcap > 8) nbcap = 8;
    if (nbcap < 1) nbcap = 1;

    unsigned short* Wb    = (unsigned short*)d_ws;
    unsigned short* qkv   = Wb    + (size_t)OC_ * C_;
    unsigned short* qkv_t = qkv   + e_qkv * nbcap;
    unsigned short* oh    = qkv_t + e_qkv * nbcap;
    unsigned short* ow    = oh    + e_out * nbcap;
    float* mh  = (float*)(ow + e_out * nbcap);
    float* sh  = mh  + e_stat * nbcap;
    float* mw  = sh  + e_stat * nbcap;
    float* sw  = mw  + e_stat * nbcap;
    float* mc  = sw  + e_stat * nbcap;
    float* dv  = mc  + e_stat * nbcap;
    float* mct = dv  + e_stat * nbcap;
    float* dvt = mct + e_stat * nbcap;

    k_wconv<<<dim3(80), 256, 0, stream>>>(wq, wk, wv, Wb);

    for (int b0 = 0; b0 < 8; b0 += nbcap) {
        int nb = 8 - b0 < nbcap ? 8 - b0 : nbcap;
        k_qkv<<<dim3(HW_ / 128, 5, nb), 256, 0, stream>>>(
            x, Wb, bq, bk, bv, qkv, b0);
        k_transpose_qkv<<<dim3(16, OC_, nb), dim3(32, 8), 0, stream>>>(qkv, qkv_t);
        k_stats_h<<<dim3(W_, nb), 128, 0, stream>>>(qkv_t, mh, sh);
        k_stats_w<<<dim3(H_, nb), 128, 0, stream>>>(qkv, mw, sw);
        int nstat = nb * HW_;
        k_prep<<<dim3((nstat + 255) / 256), 256, 0, stream>>>(
            mh, sh, mw, sw, mc, dv, mct, dvt, nstat);
        k_outh<<<dim3(W_, nb), 256, 0, stream>>>(qkv_t, mct, dvt, oh);
        k_outw<<<dim3(H_, nb), 256, 0, stream>>>(qkv, mc, dv, ow);
        k_combine<<<dim3(16, C_, nb), dim3(32, 8), 0, stream>>>(
            oh, ow, x, gm, out, b0);
    }
}

// Round 8
// 373.417 us; speedup vs baseline: 1.1269x; 1.1269x over previous
//
#include <hip/hip_runtime.h>
#include <math.h>

#define C_   256
#define CQ_  32
#define H_   128
#define W_   128
#define HW_  (H_ * W_)
#define OC_  320   // 0..31 q, 32..63 k, 64..319 v

typedef __attribute__((ext_vector_type(8))) short  s8v;   // 8 bf16 (A/B frag)
typedef __attribute__((ext_vector_type(4))) float  f4v;   // 4 fp32 (C/D frag)
typedef __attribute__((ext_vector_type(8))) unsigned short u8v;
typedef __attribute__((ext_vector_type(4))) unsigned short u4v;

__device__ inline unsigned short f2bf(float f) {
    unsigned int u = __float_as_uint(f);
    unsigned int r = (u + 0x7fffu + ((u >> 16) & 1u)) >> 16;
    return (unsigned short)r;
}
__device__ inline float bfu(unsigned short u) {
    return __uint_as_float((unsigned int)u << 16);
}

// convert ushort8 (bf16) -> 8 floats written to dst (16B-aligned)
__device__ inline void cvt8(const u8v u, float* dst) {
    float4 lo, hi;
    lo.x = bfu(u[0]); lo.y = bfu(u[1]); lo.z = bfu(u[2]); lo.w = bfu(u[3]);
    hi.x = bfu(u[4]); hi.y = bfu(u[5]); hi.z = bfu(u[6]); hi.w = bfu(u[7]);
    *(float4*)dst = lo;
    *(float4*)(dst + 4) = hi;
}

// ------------------------------------------------ K0: W -> bf16 (320x256)
__global__ __launch_bounds__(256) void k_wconv(
    const float* __restrict__ wq, const float* __restrict__ wk,
    const float* __restrict__ wv, unsigned short* __restrict__ Wb)
{
    int idx4 = blockIdx.x * 256 + threadIdx.x;     // 20480 total
    int e = idx4 * 4;
    int oc = e >> 8, k = e & 255;
    const float* src;
    if (oc < 32)      src = wq + (size_t)oc * C_ + k;
    else if (oc < 64) src = wk + (size_t)(oc - 32) * C_ + k;
    else              src = wv + (size_t)(oc - 64) * C_ + k;
    float4 v = *(const float4*)src;
    u4v o;
    o[0] = f2bf(v.x); o[1] = f2bf(v.y); o[2] = f2bf(v.z); o[3] = f2bf(v.w);
    *(u4v*)(Wb + e) = o;
}

// ---------------------------------------------------------- K1: QKV MFMA GEMM
// qkv[bb][oc][n] = W[oc,:] @ x[b0+bb][:,n] + bias[oc]   (bf16 out)
// grid (HW/128, 5, nb), block 256 (4 waves); wave tile 64oc x 32n
// v3: W in LDS (staged once, b128 reads — proven R2 path); X staged as
//     k-pair-packed bf16 dwords (0-conflict, proven R6 path); single X
//     buffer, 2 barriers / K-64 chunk, next chunk's global loads issued
//     right after barrier B so latency hides under compute (T14).
__global__ __launch_bounds__(256) void k_qkv(
    const float* __restrict__ x, const unsigned short* __restrict__ Wb,
    const float* __restrict__ bq, const float* __restrict__ bk,
    const float* __restrict__ bv,
    unsigned short* __restrict__ qkv, int b0)
{
    __shared__ __align__(16) unsigned short Wl[64][264];   // 33.8 KB bf16
    __shared__ __align__(16) unsigned int   Xp[32 * 132];  // 16.9 KB packed k-pairs
    const int t = threadIdx.x;
    const int lane = t & 63;
    const int wave = t >> 6;
    const int n0 = blockIdx.x * 128;
    const int ocblk = blockIdx.y * 64;
    const int bb = blockIdx.z;
    const float* xb = x + (size_t)(b0 + bb) * C_ * HW_;

    const int lg = lane >> 4;      // 0..3
    const int ll = lane & 15;      // 0..15
    const int n_w = wave * 32;

    const int kp8 = t >> 5;          // 0..7  (k-pair row subgroup)
    const int n4  = (t & 31) * 4;    // 0..124
    float4 ra[4], rb[4];

    // issue X loads for chunk 0 ASAP (hide under W staging)
    #pragma unroll
    for (int p = 0; p < 4; ++p) {
        int krow = (p * 8 + kp8) * 2;
        ra[p] = *(const float4*)(xb + (size_t)krow * HW_ + n0 + n4);
        rb[p] = *(const float4*)(xb + (size_t)(krow + 1) * HW_ + n0 + n4);
    }

    // stage W tile (64 oc x 256 k, bf16), once
    #pragma unroll
    for (int q = 0; q < 8; ++q) {
        int chunk = t + q * 256;           // 2048 chunks of 8
        int row = chunk >> 5;
        int col = (chunk & 31) * 8;
        u8v w = *(const u8v*)(Wb + (size_t)(ocblk + row) * C_ + col);
        *(u8v*)&Wl[row][col] = w;
    }

    f4v acc[4][2];
    #pragma unroll
    for (int mr = 0; mr < 4; ++mr)
        #pragma unroll
        for (int nr = 0; nr < 2; ++nr)
            acc[mr][nr] = (f4v){0.f, 0.f, 0.f, 0.f};

    #pragma unroll
    for (int kc = 0; kc < 4; ++kc) {
        __syncthreads();   // prev chunk's Xp reads done (also orders Wl stage at kc=0)
        // pack fp32 pair -> bf16 dword (round half-up), write b128
        #pragma unroll
        for (int p = 0; p < 4; ++p) {
            uint4 d;
            const float* af  = (const float*)&ra[p];
            const float* bf_ = (const float*)&rb[p];
            #pragma unroll
            for (int i = 0; i < 4; ++i) {
                unsigned int lo = (__float_as_uint(af[i])  + 0x8000u) >> 16;
                unsigned int hi = (__float_as_uint(bf_[i]) + 0x8000u) & 0xffff0000u;
                ((unsigned int*)&d)[i] = hi | lo;
            }
            *(uint4*)&Xp[(p * 8 + kp8) * 132 + n4] = d;
        }
        __syncthreads();   // Xp ready
        // issue next chunk's global loads — consumed only at next pack,
        // so HBM/L2 latency hides under the MFMA phase below
        if (kc < 3) {
            #pragma unroll
            for (int p = 0; p < 4; ++p) {
                int krow = (kc + 1) * 64 + (p * 8 + kp8) * 2;
                ra[p] = *(const float4*)(xb + (size_t)krow * HW_ + n0 + n4);
                rb[p] = *(const float4*)(xb + (size_t)(krow + 1) * HW_ + n0 + n4);
            }
        }
        #pragma unroll
        for (int ks = 0; ks < 2; ++ks) {
            s8v afr[4];
            #pragma unroll
            for (int mr = 0; mr < 4; ++mr)
                afr[mr] = *(const s8v*)&Wl[mr * 16 + ll][(kc * 2 + ks) * 32 + lg * 8];
            #pragma unroll
            for (int nr = 0; nr < 2; ++nr) {
                int4 bd;
                #pragma unroll
                for (int e2 = 0; e2 < 4; ++e2)
                    ((int*)&bd)[e2] =
                        Xp[(ks * 16 + lg * 4 + e2) * 132 + n_w + nr * 16 + ll];
                s8v bfr = *(s8v*)&bd;
                #pragma unroll
                for (int mr = 0; mr < 4; ++mr)
                    acc[mr][nr] = __builtin_amdgcn_mfma_f32_16x16x32_bf16(
                        afr[mr], bfr, acc[mr][nr], 0, 0, 0);
            }
        }
    }

    #pragma unroll
    for (int mr = 0; mr < 4; ++mr) {
        float bias[4];
        #pragma unroll
        for (int r = 0; r < 4; ++r) {
            int oc = ocblk + mr * 16 + lg * 4 + r;
            if (oc < 32)      bias[r] = bq[oc];
            else if (oc < 64) bias[r] = bk[oc - 32];
            else              bias[r] = bv[oc - 64];
        }
        #pragma unroll
        for (int nr = 0; nr < 2; ++nr) {
            int n = n0 + n_w + nr * 16 + ll;
            #pragma unroll
            for (int r = 0; r < 4; ++r) {
                int oc = ocblk + mr * 16 + lg * 4 + r;
                qkv[((size_t)bb * OC_ + oc) * HW_ + n] = f2bf(acc[mr][nr][r] + bias[r]);
            }
        }
    }
}

// ------------------------------------------------- K1b: transpose to (b,w,oc,h)
__global__ __launch_bounds__(256) void k_transpose_qkv(
    const unsigned short* __restrict__ qkv, unsigned short* __restrict__ qkv_t)
{
    __shared__ unsigned short tile[32][34];
    const int bb = blockIdx.z;
    const int oc = blockIdx.y;
    const int th = (blockIdx.x & 3) * 32;
    const int tw = (blockIdx.x >> 2) * 32;
    const unsigned short* src = qkv + ((size_t)bb * OC_ + oc) * HW_;
    #pragma unroll
    for (int r = 0; r < 4; ++r) {
        int h = threadIdx.y * 4 + r;
        tile[h][threadIdx.x] = src[(size_t)(th + h) * W_ + tw + threadIdx.x];
    }
    __syncthreads();
    unsigned short* dst = qkv_t + (size_t)bb * W_ * OC_ * H_;
    #pragma unroll
    for (int r = 0; r < 4; ++r) {
        int wl = threadIdx.y * 4 + r;
        dst[((size_t)(tw + wl) * OC_ + oc) * H_ + th + threadIdx.x] = tile[threadIdx.x][wl];
    }
}

// ----------------------------------------------- K2a: column (e_h) softmax stats
__global__ __launch_bounds__(128) void k_stats_h(
    const unsigned short* __restrict__ qkv_t,
    float* __restrict__ mh, float* __restrict__ sh)
{
    __shared__ __align__(16) float Qc[CQ_][H_];
    const int t = threadIdx.x;            // i
    const int beta = blockIdx.x;
    const int bb = blockIdx.y;
    const unsigned short* base = qkv_t + ((size_t)bb * W_ + beta) * OC_ * H_;
    for (int f = t * 8; f < CQ_ * H_; f += 1024)
        cvt8(*(const u8v*)(base + f), &Qc[0][f]);
    float kreg[CQ_];
    #pragma unroll
    for (int c = 0; c < CQ_; ++c) kreg[c] = bfu(base[(size_t)(32 + c) * H_ + t]);
    __syncthreads();
    float m = -INFINITY, s = 0.f;
    for (int jq = 0; jq < 32; ++jq) {
        float e[4] = {0.f, 0.f, 0.f, 0.f};
        #pragma unroll
        for (int c = 0; c < CQ_; ++c) {
            float4 q4 = *(const float4*)&Qc[c][jq * 4];
            e[0] += kreg[c] * q4.x; e[1] += kreg[c] * q4.y;
            e[2] += kreg[c] * q4.z; e[3] += kreg[c] * q4.w;
        }
        int jb = jq * 4;
        if (t >= jb && t < jb + 4) e[t - jb] = -INFINITY;  // diag mask
        float me = fmaxf(fmaxf(e[0], e[1]), fmaxf(e[2], e[3]));
        float mn = fmaxf(m, me);
        s = s * __expf(m - mn) + __expf(e[0] - mn) + __expf(e[1] - mn)
                               + __expf(e[2] - mn) + __expf(e[3] - mn);
        m = mn;
    }
    mh[((size_t)bb * H_ + t) * W_ + beta] = m;
    sh[((size_t)bb * H_ + t) * W_ + beta] = s;
}

// -------------------------------------------------- K2b: row (e_w) softmax stats
__global__ __launch_bounds__(128) void k_stats_w(
    const unsigned short* __restrict__ qkv,
    float* __restrict__ mw, float* __restrict__ sw)
{
    __shared__ __align__(16) float Qr[CQ_][W_];
    const int t = threadIdx.x;            // beta (key col)
    const int alpha = blockIdx.x;
    const int bb = blockIdx.y;
    const unsigned short* base = qkv + (size_t)bb * OC_ * HW_ + (size_t)alpha * W_;
    for (int f = t * 8; f < CQ_ * W_; f += 1024) {
        int c = f >> 7, w = f & 127;
        cvt8(*(const u8v*)(base + (size_t)c * HW_ + w), &Qr[c][w]);
    }
    float kreg[CQ_];
    #pragma unroll
    for (int c = 0; c < CQ_; ++c) kreg[c] = bfu(base[(size_t)(32 + c) * HW_ + t]);
    __syncthreads();
    float m = -INFINITY, s = 0.f;
    for (int jq = 0; jq < 32; ++jq) {
        float e[4] = {0.f, 0.f, 0.f, 0.f};
        #pragma unroll
        for (int c = 0; c < CQ_; ++c) {
            float4 q4 = *(const float4*)&Qr[c][jq * 4];
            e[0] += kreg[c] * q4.x; e[1] += kreg[c] * q4.y;
            e[2] += kreg[c] * q4.z; e[3] += kreg[c] * q4.w;
        }
        float me = fmaxf(fmaxf(e[0], e[1]), fmaxf(e[2], e[3]));
        float mn = fmaxf(m, me);
        s = s * __expf(m - mn) + __expf(e[0] - mn) + __expf(e[1] - mn)
                               + __expf(e[2] - mn) + __expf(e[3] - mn);
        m = mn;
    }
    mw[((size_t)bb * H_ + alpha) * W_ + t] = m;
    sw[((size_t)bb * H_ + alpha) * W_ + t] = s;
}

// ------------------------------- K2c: combine stats -> m_comb, d_inv (+transposed)
// idx = (b*H + p)*W + q  (key position p=row, q=col)
__global__ __launch_bounds__(256) void k_prep(
    const float* __restrict__ mh, const float* __restrict__ sh,
    const float* __restrict__ mw, const float* __restrict__ sw,
    float* __restrict__ mc, float* __restrict__ dv,
    float* __restrict__ mct, float* __restrict__ dvt, int n)
{
    int idx = blockIdx.x * 256 + threadIdx.x;
    if (idx >= n) return;
    float m1 = mh[idx], s1 = sh[idx], m2 = mw[idx], s2 = sw[idx];
    float m = fmaxf(m1, m2);
    float d = 1.f / (s1 * __expf(m1 - m) + s2 * __expf(m2 - m));
    mc[idx] = m; dv[idx] = d;
    int q = idx & (W_ - 1);
    int p = (idx >> 7) & (H_ - 1);
    int b = idx >> 14;
    size_t tid = ((size_t)b * W_ + q) * H_ + p;
    mct[tid] = m; dvt[tid] = d;
}

// -------------------------------------------------------------- K3: out_h (MFMA)
// per (b, beta): oh_t[b][beta][c][j] = sum_i V(c,i) P(i,j)   (bf16 out)
// grid (W, nb), block 256 (4 waves)
__global__ __launch_bounds__(256) void k_outh(
    const unsigned short* __restrict__ qkv_t,
    const float* __restrict__ mct, const float* __restrict__ dvt,
    unsigned short* __restrict__ oh_t)
{
    __shared__ __align__(16) unsigned short Pt[128 * 128];   // swizzled, 32 KB
    __shared__ __align__(16) unsigned char  Ubuf[32 * 132 * 4]; // Qf fp32 | V chunk
    __shared__ float mloc[128], dloc[128];
    float* Qf = (float*)Ubuf;                    // [32][132]
    unsigned short* Vl = (unsigned short*)Ubuf;  // [64][128] swizzled

    const int t = threadIdx.x;
    const int beta = blockIdx.x;
    const int bb = blockIdx.y;
    const unsigned short* base = qkv_t + ((size_t)bb * W_ + beta) * OC_ * H_;

    if (t < 128) {
        size_t sidx = ((size_t)bb * W_ + beta) * H_ + t;
        mloc[t] = mct[sidx];
        dloc[t] = dvt[sidx];
    }
    // stage Q (32 x 128) fp32
    for (int f = t * 8; f < CQ_ * H_; f += 2048) {
        int c = f >> 7, j = f & 127;
        cvt8(*(const u8v*)(base + f), &Qf[c * 132 + j]);
    }
    // K column i in registers
    const int i = t & 127;
    const int jg = t >> 7;
    float kreg[CQ_];
    #pragma unroll
    for (int c = 0; c < CQ_; ++c) kreg[c] = bfu(base[(size_t)(32 + c) * H_ + i]);
    __syncthreads();

    const float m = mloc[i], dv = dloc[i];
    // e + softmax -> Pt[j][i] (bf16, XOR-swizzled)
    for (int jq = 0; jq < 16; ++jq) {
        int j = jg * 64 + jq * 4;
        float e[4] = {0.f, 0.f, 0.f, 0.f};
        #pragma unroll
        for (int c = 0; c < CQ_; ++c) {
            float4 q4 = *(const float4*)&Qf[c * 132 + j];
            e[0] += kreg[c] * q4.x; e[1] += kreg[c] * q4.y;
            e[2] += kreg[c] * q4.z; e[3] += kreg[c] * q4.w;
        }
        #pragma unroll
        for (int u = 0; u < 4; ++u) {
            int jj = j + u;
            float p = (jj == i) ? 0.f : __expf(e[u] - m) * dv;
            Pt[(jj * 128 + i) ^ ((jj & 7) << 3)] = f2bf(p);
        }
    }

    const int lane = t & 63;
    const int wv = t >> 6;
    const int lg = lane >> 4;
    const int ll = lane & 15;
    unsigned short* outbase = oh_t + ((size_t)bb * W_ + beta) * C_ * H_;

    for (int ch = 0; ch < 4; ++ch) {
        __syncthreads();
        // stage V chunk: rows c in [ch*64, ch*64+64)
        const unsigned short* vsrc = base + (size_t)(64 + ch * 64) * H_;
        #pragma unroll
        for (int f = t; f < 1024; f += 256) {
            int c = f >> 4, i0 = (f & 15) * 8;
            u8v v = *(const u8v*)(vsrc + (size_t)c * H_ + i0);
            *(u8v*)&Vl[(c * 128 + i0) ^ ((c & 7) << 3)] = v;
        }
        __syncthreads();

        f4v acc[8];
        #pragma unroll
        for (int nt = 0; nt < 8; ++nt) acc[nt] = (f4v){0.f, 0.f, 0.f, 0.f};

        #pragma unroll
        for (int kk = 0; kk < 4; ++kk) {
            int crow = wv * 16 + ll;
            s8v afr = *(const s8v*)&Vl[(crow * 128 + kk * 32 + lg * 8) ^ ((crow & 7) << 3)];
            #pragma unroll
            for (int nt = 0; nt < 8; ++nt) {
                int j = nt * 16 + ll;
                s8v bfr = *(const s8v*)&Pt[(j * 128 + kk * 32 + lg * 8) ^ ((j & 7) << 3)];
                acc[nt] = __builtin_amdgcn_mfma_f32_16x16x32_bf16(afr, bfr, acc[nt], 0, 0, 0);
            }
        }
        // store: c = ch*64 + wv*16 + lg*4 + r, j = nt*16 + ll
        #pragma unroll
        for (int nt = 0; nt < 8; ++nt) {
            int j = nt * 16 + ll;
            #pragma unroll
            for (int r = 0; r < 4; ++r) {
                int c = ch * 64 + wv * 16 + lg * 4 + r;
                outbase[(size_t)c * H_ + j] = f2bf(acc[nt][r]);
            }
        }
    }
}

// -------------------------------------------------------------- K4: out_w (MFMA)
// per (b, alpha): ow[b][c][alpha][j] = sum_i V(c,i) Pw(i,j)   (bf16 out)
__global__ __launch_bounds__(256) void k_outw(
    const unsigned short* __restrict__ qkv,
    const float* __restrict__ mc, const float* __restrict__ dv_,
    unsigned short* __restrict__ ow)
{
    __shared__ __align__(16) unsigned short Pt[128 * 128];
    __shared__ __align__(16) unsigned char  Ubuf[32 * 132 * 4];
    __shared__ float mloc[128], dloc[128];
    float* Qf = (float*)Ubuf;
    unsigned short* Vl = (unsigned short*)Ubuf;

    const int t = threadIdx.x;
    const int alpha = blockIdx.x;
    const int bb = blockIdx.y;
    const unsigned short* base = qkv + (size_t)bb * OC_ * HW_ + (size_t)alpha * W_;

    if (t < 128) {
        size_t sidx = ((size_t)bb * H_ + alpha) * W_ + t;
        mloc[t] = mc[sidx];
        dloc[t] = dv_[sidx];
    }
    for (int f = t * 8; f < CQ_ * W_; f += 2048) {
        int c = f >> 7, j = f & 127;
        cvt8(*(const u8v*)(base + (size_t)c * HW_ + j), &Qf[c * 132 + j]);
    }
    const int i = t & 127;
    const int jg = t >> 7;
    float kreg[CQ_];
    #pragma unroll
    for (int c = 0; c < CQ_; ++c) kreg[c] = bfu(base[(size_t)(32 + c) * HW_ + i]);
    __syncthreads();

    const float m = mloc[i], dv = dloc[i];
    for (int jq = 0; jq < 16; ++jq) {
        int j = jg * 64 + jq * 4;
        float e[4] = {0.f, 0.f, 0.f, 0.f};
        #pragma unroll
        for (int c = 0; c < CQ_; ++c) {
            float4 q4 = *(const float4*)&Qf[c * 132 + j];
            e[0] += kreg[c] * q4.x; e[1] += kreg[c] * q4.y;
            e[2] += kreg[c] * q4.z; e[3] += kreg[c] * q4.w;
        }
        #pragma unroll
        for (int u = 0; u < 4; ++u) {
            int jj = j + u;
            float p = __expf(e[u] - m) * dv;     // no diag mask in e_w
            Pt[(jj * 128 + i) ^ ((jj & 7) << 3)] = f2bf(p);
        }
    }

    const int lane = t & 63;
    const int wv = t >> 6;
    const int lg = lane >> 4;
    const int ll = lane & 15;
    unsigned short* obase = ow + (size_t)bb * C_ * HW_ + (size_t)alpha * W_;

    for (int ch = 0; ch < 4; ++ch) {
        __syncthreads();
        const unsigned short* vsrc = base + (size_t)(64 + ch * 64) * HW_;
        #pragma unroll
        for (int f = t; f < 1024; f += 256) {
            int c = f >> 4, i0 = (f & 15) * 8;
            u8v v = *(const u8v*)(vsrc + (size_t)c * HW_ + i0);
            *(u8v*)&Vl[(c * 128 + i0) ^ ((c & 7) << 3)] = v;
        }
        __syncthreads();

        f4v acc[8];
        #pragma unroll
        for (int nt = 0; nt < 8; ++nt) acc[nt] = (f4v){0.f, 0.f, 0.f, 0.f};

        #pragma unroll
        for (int kk = 0; kk < 4; ++kk) {
            int crow = wv * 16 + ll;
            s8v afr = *(const s8v*)&Vl[(crow * 128 + kk * 32 + lg * 8) ^ ((crow & 7) << 3)];
            #pragma unroll
            for (int nt = 0; nt < 8; ++nt) {
                int j = nt * 16 + ll;
                s8v bfr = *(const s8v*)&Pt[(j * 128 + kk * 32 + lg * 8) ^ ((j & 7) << 3)];
                acc[nt] = __builtin_amdgcn_mfma_f32_16x16x32_bf16(afr, bfr, acc[nt], 0, 0, 0);
            }
        }
        #pragma unroll
        for (int nt = 0; nt < 8; ++nt) {
            int j = nt * 16 + ll;
            #pragma unroll
            for (int r = 0; r < 4; ++r) {
                int c = ch * 64 + wv * 16 + lg * 4 + r;
                obase[(size_t)c * HW_ + j] = f2bf(acc[nt][r]);
            }
        }
    }
}

// ------------------------------- K5: out = x + gamma*(ow + oh^T)  (fused epilogue)
__global__ __launch_bounds__(256) void k_combine(
    const unsigned short* __restrict__ oh_t, const unsigned short* __restrict__ ow,
    const float* __restrict__ x, const float* __restrict__ gamma_p,
    float* __restrict__ out, int b0)
{
    __shared__ float tile[32][33];
    const int bb = blockIdx.z;
    const int c = blockIdx.y;
    const int th = (blockIdx.x & 3) * 32;
    const int tw = (blockIdx.x >> 2) * 32;
    const float gamma = gamma_p[0];
    const unsigned short* src = oh_t + (size_t)bb * W_ * C_ * H_;
    #pragma unroll
    for (int r = 0; r < 4; ++r) {
        int wl = threadIdx.y * 4 + r;
        tile[wl][threadIdx.x] =
            bfu(src[((size_t)(tw + wl) * C_ + c) * H_ + th + threadIdx.x]);
    }
    __syncthreads();
    const size_t pbase = ((size_t)bb * C_ + c) * HW_;
    const size_t gbase = ((size_t)(b0 + bb) * C_ + c) * HW_;
    #pragma unroll
    for (int r = 0; r < 4; ++r) {
        int hl = threadIdx.y * 4 + r;
        size_t idx = (size_t)(th + hl) * W_ + tw + threadIdx.x;
        float owv = bfu(ow[pbase + idx]);
        out[gbase + idx] = x[gbase + idx] + gamma * (owv + tile[threadIdx.x][hl]);
    }
}

// ------------------------------------------------------------------- launcher
extern "C" void kernel_launch(void* const* d_in, const int* in_sizes, int n_in,
                              void* d_out, int out_size, void* d_ws, size_t ws_size,
                              hipStream_t stream)
{
    (void)in_sizes; (void)n_in; (void)out_size;
    const float* x  = (const float*)d_in[0];
    const float* wq = (const float*)d_in[1];
    const float* bq = (const float*)d_in[2];
    const float* wk = (const float*)d_in[3];
    const float* bk = (const float*)d_in[4];
    const float* wv = (const float*)d_in[5];
    const float* bv = (const float*)d_in[6];
    const float* gm = (const float*)d_in[7];
    float* out = (float*)d_out;

    const size_t e_qkv  = (size_t)OC_ * HW_;   // bf16 elements
    const size_t e_out  = (size_t)C_ * HW_;    // bf16 elements
    const size_t e_stat = (size_t)HW_;         // fp32 elements
    const size_t perb_bytes = (e_qkv * 2 + e_out * 2) * 2 + e_stat * 8 * 4;
    const size_t wb_bytes = (size_t)OC_ * C_ * 2;
    int nbcap = (int)((ws_size - wb_bytes) / perb_bytes);
    if (nbcap > 8) nbcap = 8;
    if (nbcap < 1) nbcap = 1;

    unsigned short* Wb    = (unsigned short*)d_ws;
    unsigned short* qkv   = Wb    + (size_t)OC_ * C_;
    unsigned short* qkv_t = qkv   + e_qkv * nbcap;
    unsigned short* oh    = qkv_t + e_qkv * nbcap;
    unsigned short* ow    = oh    + e_out * nbcap;
    float* mh  = (float*)(ow + e_out * nbcap);
    float* sh  = mh  + e_stat * nbcap;
    float* mw  = sh  + e_stat * nbcap;
    float* sw  = mw  + e_stat * nbcap;
    float* mc  = sw  + e_stat * nbcap;
    float* dv  = mc  + e_stat * nbcap;
    float* mct = dv  + e_stat * nbcap;
    float* dvt = mct + e_stat * nbcap;

    k_wconv<<<dim3(80), 256, 0, stream>>>(wq, wk, wv, Wb);

    for (int b0 = 0; b0 < 8; b0 += nbcap) {
        int nb = 8 - b0 < nbcap ? 8 - b0 : nbcap;
        k_qkv<<<dim3(HW_ / 128, 5, nb), 256, 0, stream>>>(
            x, Wb, bq, bk, bv, qkv, b0);
        k_transpose_qkv<<<dim3(16, OC_, nb), dim3(32, 8), 0, stream>>>(qkv, qkv_t);
        k_stats_h<<<dim3(W_, nb), 128, 0, stream>>>(qkv_t, mh, sh);
        k_stats_w<<<dim3(H_, nb), 128, 0, stream>>>(qkv, mw, sw);
        int nstat = nb * HW_;
        k_prep<<<dim3((nstat + 255) / 256), 256, 0, stream>>>(
            mh, sh, mw, sw, mc, dv, mct, dvt, nstat);
        k_outh<<<dim3(W_, nb), 256, 0, stream>>>(qkv_t, mct, dvt, oh);
        k_outw<<<dim3(H_, nb), 256, 0, stream>>>(qkv, mc, dv, ow);
        k_combine<<<dim3(16, C_, nb), dim3(32, 8), 0, stream>>>(
            oh, ow, x, gm, out, b0);
    }
}

// Round 9
// 308.580 us; speedup vs baseline: 1.3637x; 1.2101x over previous
//
#include <hip/hip_runtime.h>
#include <math.h>

#define C_   256
#define CQ_  32
#define H_   128
#define W_   128
#define HW_  (H_ * W_)
#define OC_  320   // 0..31 q, 32..63 k, 64..319 v

typedef __attribute__((ext_vector_type(8))) short  s8v;   // 8 bf16 (A/B frag)
typedef __attribute__((ext_vector_type(4))) float  f4v;   // 4 fp32 (C/D frag)
typedef __attribute__((ext_vector_type(8))) unsigned short u8v;
typedef __attribute__((ext_vector_type(4))) unsigned short u4v;

__device__ inline unsigned short f2bf(float f) {
    unsigned int u = __float_as_uint(f);
    unsigned int r = (u + 0x7fffu + ((u >> 16) & 1u)) >> 16;
    return (unsigned short)r;
}
__device__ inline float bfu(unsigned short u) {
    return __uint_as_float((unsigned int)u << 16);
}

// ------------------------------------------------ K0: W -> bf16 (320x256)
__global__ __launch_bounds__(256) void k_wconv(
    const float* __restrict__ wq, const float* __restrict__ wk,
    const float* __restrict__ wv, unsigned short* __restrict__ Wb)
{
    int idx4 = blockIdx.x * 256 + threadIdx.x;     // 20480 total
    int e = idx4 * 4;
    int oc = e >> 8, k = e & 255;
    const float* src;
    if (oc < 32)      src = wq + (size_t)oc * C_ + k;
    else if (oc < 64) src = wk + (size_t)(oc - 32) * C_ + k;
    else              src = wv + (size_t)(oc - 64) * C_ + k;
    float4 v = *(const float4*)src;
    u4v o;
    o[0] = f2bf(v.x); o[1] = f2bf(v.y); o[2] = f2bf(v.z); o[3] = f2bf(v.w);
    *(u4v*)(Wb + e) = o;
}

// ---------------------------------------------------------- K1: QKV MFMA GEMM
// (unchanged from R7 — 90 µs, proven)
__global__ __launch_bounds__(256) void k_qkv(
    const float* __restrict__ x, const unsigned short* __restrict__ Wb,
    const float* __restrict__ bq, const float* __restrict__ bk,
    const float* __restrict__ bv,
    unsigned short* __restrict__ qkv, int b0)
{
    __shared__ __align__(16) unsigned short Wl[64][264];   // 33.8 KB bf16
    __shared__ __align__(16) unsigned int   Xp[32 * 132];  // 16.9 KB packed k-pairs
    const int t = threadIdx.x;
    const int lane = t & 63;
    const int wave = t >> 6;
    const int n0 = blockIdx.x * 128;
    const int ocblk = blockIdx.y * 64;
    const int bb = blockIdx.z;
    const float* xb = x + (size_t)(b0 + bb) * C_ * HW_;

    const int lg = lane >> 4;      // 0..3
    const int ll = lane & 15;      // 0..15
    const int n_w = wave * 32;

    const int kp8 = t >> 5;          // 0..7
    const int n4  = (t & 31) * 4;    // 0..124
    float4 ra[4], rb[4];

    #pragma unroll
    for (int p = 0; p < 4; ++p) {
        int krow = (p * 8 + kp8) * 2;
        ra[p] = *(const float4*)(xb + (size_t)krow * HW_ + n0 + n4);
        rb[p] = *(const float4*)(xb + (size_t)(krow + 1) * HW_ + n0 + n4);
    }

    #pragma unroll
    for (int q = 0; q < 8; ++q) {
        int chunk = t + q * 256;
        int row = chunk >> 5;
        int col = (chunk & 31) * 8;
        u8v w = *(const u8v*)(Wb + (size_t)(ocblk + row) * C_ + col);
        *(u8v*)&Wl[row][col] = w;
    }

    f4v acc[4][2];
    #pragma unroll
    for (int mr = 0; mr < 4; ++mr)
        #pragma unroll
        for (int nr = 0; nr < 2; ++nr)
            acc[mr][nr] = (f4v){0.f, 0.f, 0.f, 0.f};

    #pragma unroll
    for (int kc = 0; kc < 4; ++kc) {
        __syncthreads();
        #pragma unroll
        for (int p = 0; p < 4; ++p) {
            uint4 d;
            const float* af  = (const float*)&ra[p];
            const float* bf_ = (const float*)&rb[p];
            #pragma unroll
            for (int i = 0; i < 4; ++i) {
                unsigned int lo = (__float_as_uint(af[i])  + 0x8000u) >> 16;
                unsigned int hi = (__float_as_uint(bf_[i]) + 0x8000u) & 0xffff0000u;
                ((unsigned int*)&d)[i] = hi | lo;
            }
            *(uint4*)&Xp[(p * 8 + kp8) * 132 + n4] = d;
        }
        __syncthreads();
        if (kc < 3) {
            #pragma unroll
            for (int p = 0; p < 4; ++p) {
                int krow = (kc + 1) * 64 + (p * 8 + kp8) * 2;
                ra[p] = *(const float4*)(xb + (size_t)krow * HW_ + n0 + n4);
                rb[p] = *(const float4*)(xb + (size_t)(krow + 1) * HW_ + n0 + n4);
            }
        }
        #pragma unroll
        for (int ks = 0; ks < 2; ++ks) {
            s8v afr[4];
            #pragma unroll
            for (int mr = 0; mr < 4; ++mr)
                afr[mr] = *(const s8v*)&Wl[mr * 16 + ll][(kc * 2 + ks) * 32 + lg * 8];
            #pragma unroll
            for (int nr = 0; nr < 2; ++nr) {
                int4 bd;
                #pragma unroll
                for (int e2 = 0; e2 < 4; ++e2)
                    ((int*)&bd)[e2] =
                        Xp[(ks * 16 + lg * 4 + e2) * 132 + n_w + nr * 16 + ll];
                s8v bfr = *(s8v*)&bd;
                #pragma unroll
                for (int mr = 0; mr < 4; ++mr)
                    acc[mr][nr] = __builtin_amdgcn_mfma_f32_16x16x32_bf16(
                        afr[mr], bfr, acc[mr][nr], 0, 0, 0);
            }
        }
    }

    #pragma unroll
    for (int mr = 0; mr < 4; ++mr) {
        float bias[4];
        #pragma unroll
        for (int r = 0; r < 4; ++r) {
            int oc = ocblk + mr * 16 + lg * 4 + r;
            if (oc < 32)      bias[r] = bq[oc];
            else if (oc < 64) bias[r] = bk[oc - 32];
            else              bias[r] = bv[oc - 64];
        }
        #pragma unroll
        for (int nr = 0; nr < 2; ++nr) {
            int n = n0 + n_w + nr * 16 + ll;
            #pragma unroll
            for (int r = 0; r < 4; ++r) {
                int oc = ocblk + mr * 16 + lg * 4 + r;
                qkv[((size_t)bb * OC_ + oc) * HW_ + n] = f2bf(acc[mr][nr][r] + bias[r]);
            }
        }
    }
}

// ------------------------------------------------- K1b: transpose to (b,w,oc,h)
__global__ __launch_bounds__(256) void k_transpose_qkv(
    const unsigned short* __restrict__ qkv, unsigned short* __restrict__ qkv_t)
{
    __shared__ unsigned short tile[32][34];
    const int bb = blockIdx.z;
    const int oc = blockIdx.y;
    const int th = (blockIdx.x & 3) * 32;
    const int tw = (blockIdx.x >> 2) * 32;
    const unsigned short* src = qkv + ((size_t)bb * OC_ + oc) * HW_;
    #pragma unroll
    for (int r = 0; r < 4; ++r) {
        int h = threadIdx.y * 4 + r;
        tile[h][threadIdx.x] = src[(size_t)(th + h) * W_ + tw + threadIdx.x];
    }
    __syncthreads();
    unsigned short* dst = qkv_t + (size_t)bb * W_ * OC_ * H_;
    #pragma unroll
    for (int r = 0; r < 4; ++r) {
        int wl = threadIdx.y * 4 + r;
        dst[((size_t)(tw + wl) * OC_ + oc) * H_ + th + threadIdx.x] = tile[threadIdx.x][wl];
    }
}

// ---------------------------------------------------------------- shared helpers
// Stage K (rows 32..63) transposed+pair-packed -> Ktp[i][c2], pitch 20 dwords
// Stage Q (rows 0..31)  pair-packed            -> Qp[c2][j],  pitch 132 dwords
// (dword low short = even c — same convention as k_qkv's Xp, HW-verified)
__device__ inline void stage_KQ(const unsigned short* base, int cstride,
                                unsigned int* Ktp, unsigned int* Qp, int t)
{
    {   // Ktp: 128 rows x 2 halves = 256 units
        int i = t & 127, half = t >> 7, c0 = half * 16;
        unsigned int kr[16];
        #pragma unroll
        for (int cc = 0; cc < 16; ++cc)
            kr[cc] = base[(size_t)(32 + c0 + cc) * cstride + i];
        uint4 d0, d1;
        #pragma unroll
        for (int e2 = 0; e2 < 4; ++e2)
            ((unsigned int*)&d0)[e2] = kr[2 * e2] | (kr[2 * e2 + 1] << 16);
        #pragma unroll
        for (int e2 = 0; e2 < 4; ++e2)
            ((unsigned int*)&d1)[e2] = kr[8 + 2 * e2] | (kr[9 + 2 * e2] << 16);
        *(uint4*)&Ktp[i * 20 + half * 8]     = d0;
        *(uint4*)&Ktp[i * 20 + half * 8 + 4] = d1;
    }
    {   // Qp: 16 c2 x 16 j-groups = 256 units
        int c2 = t >> 4, j8 = (t & 15) * 8;
        u8v qa = *(const u8v*)(base + (size_t)(2 * c2) * cstride + j8);
        u8v qb = *(const u8v*)(base + (size_t)(2 * c2 + 1) * cstride + j8);
        uint4 e0, e1;
        #pragma unroll
        for (int e = 0; e < 4; ++e)
            ((unsigned int*)&e0)[e] =
                (unsigned int)qa[e] | ((unsigned int)qb[e] << 16);
        #pragma unroll
        for (int e = 0; e < 4; ++e)
            ((unsigned int*)&e1)[e] =
                (unsigned int)qa[4 + e] | ((unsigned int)qb[4 + e] << 16);
        *(uint4*)&Qp[c2 * 132 + j8]     = e0;
        *(uint4*)&Qp[c2 * 132 + j8 + 4] = e1;
    }
}

// e-tile MFMA: e[i = mr*16 + lg*4 + r][j] for this lane (D: row=lg*4+r, col=ll)
__device__ inline f4v eqk_mfma(const unsigned int* Ktp, const unsigned int* Qp,
                               int mr, int j, int lg, int ll)
{
    s8v afr = *(const s8v*)&Ktp[(mr * 16 + ll) * 20 + lg * 4];
    int4 bd;
    #pragma unroll
    for (int e2 = 0; e2 < 4; ++e2)
        ((int*)&bd)[e2] = Qp[(lg * 4 + e2) * 132 + j];
    s8v bfr = *(s8v*)&bd;
    return __builtin_amdgcn_mfma_f32_16x16x32_bf16(
        afr, bfr, (f4v){0.f, 0.f, 0.f, 0.f}, 0, 0, 0);
}

// ----------------------------------------------- K2a: column (e_h) stats (MFMA)
// grid (W, nb), block 256 (4 waves); wave owns i-range wv*32..+32, all j
__global__ __launch_bounds__(256) void k_stats_h(
    const unsigned short* __restrict__ qkv_t,
    float* __restrict__ mh, float* __restrict__ sh)
{
    __shared__ __align__(16) unsigned int Ktp[128 * 20];
    __shared__ __align__(16) unsigned int Qp[16 * 132];
    const int t = threadIdx.x;
    const int beta = blockIdx.x;
    const int bb = blockIdx.y;
    const unsigned short* base = qkv_t + ((size_t)bb * W_ + beta) * OC_ * H_;
    stage_KQ(base, H_, Ktp, Qp, t);
    __syncthreads();

    const int lane = t & 63;
    const int wv = t >> 6;
    const int lg = lane >> 4;
    const int ll = lane & 15;

    #pragma unroll
    for (int ml = 0; ml < 2; ++ml) {
        const int mr = wv * 2 + ml;
        const int i0 = mr * 16 + lg * 4;
        f4v ef[8];
        #pragma unroll
        for (int nt = 0; nt < 8; ++nt) {
            f4v e = eqk_mfma(Ktp, Qp, mr, nt * 16 + ll, lg, ll);
            int j = nt * 16 + ll;
            #pragma unroll
            for (int r = 0; r < 4; ++r)
                if (i0 + r == j) e[r] = -INFINITY;   // diag mask
            ef[nt] = e;
        }
        #pragma unroll
        for (int r = 0; r < 4; ++r) {
            float mm = -INFINITY;
            #pragma unroll
            for (int nt = 0; nt < 8; ++nt) mm = fmaxf(mm, ef[nt][r]);
            #pragma unroll
            for (int s = 1; s < 16; s <<= 1) mm = fmaxf(mm, __shfl_xor(mm, s));
            float ss = 0.f;
            #pragma unroll
            for (int nt = 0; nt < 8; ++nt) ss += __expf(ef[nt][r] - mm);
            #pragma unroll
            for (int s = 1; s < 16; s <<= 1) ss += __shfl_xor(ss, s);
            if (ll == 0) {
                int i = i0 + r;
                mh[((size_t)bb * H_ + i) * W_ + beta] = mm;
                sh[((size_t)bb * H_ + i) * W_ + beta] = ss;
            }
        }
    }
}

// -------------------------------------------------- K2b: row (e_w) stats (MFMA)
__global__ __launch_bounds__(256) void k_stats_w(
    const unsigned short* __restrict__ qkv,
    float* __restrict__ mw, float* __restrict__ sw)
{
    __shared__ __align__(16) unsigned int Ktp[128 * 20];
    __shared__ __align__(16) unsigned int Qp[16 * 132];
    const int t = threadIdx.x;
    const int alpha = blockIdx.x;
    const int bb = blockIdx.y;
    const unsigned short* base = qkv + (size_t)bb * OC_ * HW_ + (size_t)alpha * W_;
    stage_KQ(base, HW_, Ktp, Qp, t);
    __syncthreads();

    const int lane = t & 63;
    const int wv = t >> 6;
    const int lg = lane >> 4;
    const int ll = lane & 15;

    #pragma unroll
    for (int ml = 0; ml < 2; ++ml) {
        const int mr = wv * 2 + ml;
        const int i0 = mr * 16 + lg * 4;
        f4v ef[8];
        #pragma unroll
        for (int nt = 0; nt < 8; ++nt)
            ef[nt] = eqk_mfma(Ktp, Qp, mr, nt * 16 + ll, lg, ll);
        #pragma unroll
        for (int r = 0; r < 4; ++r) {
            float mm = -INFINITY;
            #pragma unroll
            for (int nt = 0; nt < 8; ++nt) mm = fmaxf(mm, ef[nt][r]);
            #pragma unroll
            for (int s = 1; s < 16; s <<= 1) mm = fmaxf(mm, __shfl_xor(mm, s));
            float ss = 0.f;
            #pragma unroll
            for (int nt = 0; nt < 8; ++nt) ss += __expf(ef[nt][r] - mm);
            #pragma unroll
            for (int s = 1; s < 16; s <<= 1) ss += __shfl_xor(ss, s);
            if (ll == 0) {
                int i = i0 + r;
                mw[((size_t)bb * H_ + alpha) * W_ + i] = mm;
                sw[((size_t)bb * H_ + alpha) * W_ + i] = ss;
            }
        }
    }
}

// ------------------------------- K2c: combine stats -> m_comb, d_inv (+transposed)
__global__ __launch_bounds__(256) void k_prep(
    const float* __restrict__ mh, const float* __restrict__ sh,
    const float* __restrict__ mw, const float* __restrict__ sw,
    float* __restrict__ mc, float* __restrict__ dv,
    float* __restrict__ mct, float* __restrict__ dvt, int n)
{
    int idx = blockIdx.x * 256 + threadIdx.x;
    if (idx >= n) return;
    float m1 = mh[idx], s1 = sh[idx], m2 = mw[idx], s2 = sw[idx];
    float m = fmaxf(m1, m2);
    float d = 1.f / (s1 * __expf(m1 - m) + s2 * __expf(m2 - m));
    mc[idx] = m; dv[idx] = d;
    int q = idx & (W_ - 1);
    int p = (idx >> 7) & (H_ - 1);
    int b = idx >> 14;
    size_t tid = ((size_t)b * W_ + q) * H_ + p;
    mct[tid] = m; dvt[tid] = d;
}

// -------------------------------------------------------------- K3: out_h (MFMA)
// grid (W, nb), block 256 (4 waves); QK^T now MFMA, P via b64 into swizzled Pt
__global__ __launch_bounds__(256) void k_outh(
    const unsigned short* __restrict__ qkv_t,
    const float* __restrict__ mct, const float* __restrict__ dvt,
    unsigned short* __restrict__ oh_t)
{
    __shared__ __align__(16) unsigned short Pt[128 * 128];   // swizzled, 32 KB
    __shared__ __align__(16) unsigned char  Ubuf[18688];     // Ktp+Qp | Vl
    __shared__ float mloc[128], dloc[128];
    unsigned int* Ktp = (unsigned int*)Ubuf;                 // [128][20]
    unsigned int* Qp  = (unsigned int*)(Ubuf + 10240);       // [16][132]
    unsigned short* Vl = (unsigned short*)Ubuf;              // [64][128] swizzled

    const int t = threadIdx.x;
    const int beta = blockIdx.x;
    const int bb = blockIdx.y;
    const unsigned short* base = qkv_t + ((size_t)bb * W_ + beta) * OC_ * H_;

    if (t < 128) {
        size_t sidx = ((size_t)bb * W_ + beta) * H_ + t;
        mloc[t] = mct[sidx];
        dloc[t] = dvt[sidx];
    }
    stage_KQ(base, H_, Ktp, Qp, t);
    __syncthreads();

    const int lane = t & 63;
    const int wv = t >> 6;
    const int lg = lane >> 4;
    const int ll = lane & 15;
    const int jq0 = wv * 32;

    // QK^T via MFMA + in-register softmax -> Pt (b64 writes, swizzle-compatible)
    #pragma unroll
    for (int mr = 0; mr < 8; ++mr) {
        const int i0 = mr * 16 + lg * 4;
        float mi[4], di[4];
        #pragma unroll
        for (int r = 0; r < 4; ++r) { mi[r] = mloc[i0 + r]; di[r] = dloc[i0 + r]; }
        #pragma unroll
        for (int nt = 0; nt < 2; ++nt) {
            int j = jq0 + nt * 16 + ll;
            f4v e = eqk_mfma(Ktp, Qp, mr, j, lg, ll);
            float p0 = (i0     == j) ? 0.f : __expf(e[0] - mi[0]) * di[0];
            float p1 = (i0 + 1 == j) ? 0.f : __expf(e[1] - mi[1]) * di[1];
            float p2 = (i0 + 2 == j) ? 0.f : __expf(e[2] - mi[2]) * di[2];
            float p3 = (i0 + 3 == j) ? 0.f : __expf(e[3] - mi[3]) * di[3];
            uint2 wd;
            wd.x = f2bf(p0) | ((unsigned int)f2bf(p1) << 16);
            wd.y = f2bf(p2) | ((unsigned int)f2bf(p3) << 16);
            int sidx = (j * 128 + i0) ^ ((j & 7) << 3);
            *(uint2*)&Pt[sidx] = wd;
        }
    }

    unsigned short* outbase = oh_t + ((size_t)bb * W_ + beta) * C_ * H_;

    for (int ch = 0; ch < 4; ++ch) {
        __syncthreads();
        const unsigned short* vsrc = base + (size_t)(64 + ch * 64) * H_;
        #pragma unroll
        for (int f = t; f < 1024; f += 256) {
            int c = f >> 4, i0 = (f & 15) * 8;
            u8v v = *(const u8v*)(vsrc + (size_t)c * H_ + i0);
            *(u8v*)&Vl[(c * 128 + i0) ^ ((c & 7) << 3)] = v;
        }
        __syncthreads();

        f4v acc[8];
        #pragma unroll
        for (int nt = 0; nt < 8; ++nt) acc[nt] = (f4v){0.f, 0.f, 0.f, 0.f};

        #pragma unroll
        for (int kk = 0; kk < 4; ++kk) {
            int crow = wv * 16 + ll;
            s8v afr = *(const s8v*)&Vl[(crow * 128 + kk * 32 + lg * 8) ^ ((crow & 7) << 3)];
            #pragma unroll
            for (int nt = 0; nt < 8; ++nt) {
                int j = nt * 16 + ll;
                s8v bfr = *(const s8v*)&Pt[(j * 128 + kk * 32 + lg * 8) ^ ((j & 7) << 3)];
                acc[nt] = __builtin_amdgcn_mfma_f32_16x16x32_bf16(afr, bfr, acc[nt], 0, 0, 0);
            }
        }
        #pragma unroll
        for (int nt = 0; nt < 8; ++nt) {
            int j = nt * 16 + ll;
            #pragma unroll
            for (int r = 0; r < 4; ++r) {
                int c = ch * 64 + wv * 16 + lg * 4 + r;
                outbase[(size_t)c * H_ + j] = f2bf(acc[nt][r]);
            }
        }
    }
}

// -------------------------------------------------------------- K4: out_w (MFMA)
__global__ __launch_bounds__(256) void k_outw(
    const unsigned short* __restrict__ qkv,
    const float* __restrict__ mc, const float* __restrict__ dv_,
    unsigned short* __restrict__ ow)
{
    __shared__ __align__(16) unsigned short Pt[128 * 128];
    __shared__ __align__(16) unsigned char  Ubuf[18688];
    __shared__ float mloc[128], dloc[128];
    unsigned int* Ktp = (unsigned int*)Ubuf;
    unsigned int* Qp  = (unsigned int*)(Ubuf + 10240);
    unsigned short* Vl = (unsigned short*)Ubuf;

    const int t = threadIdx.x;
    const int alpha = blockIdx.x;
    const int bb = blockIdx.y;
    const unsigned short* base = qkv + (size_t)bb * OC_ * HW_ + (size_t)alpha * W_;

    if (t < 128) {
        size_t sidx = ((size_t)bb * H_ + alpha) * W_ + t;
        mloc[t] = mc[sidx];
        dloc[t] = dv_[sidx];
    }
    stage_KQ(base, HW_, Ktp, Qp, t);
    __syncthreads();

    const int lane = t & 63;
    const int wv = t >> 6;
    const int lg = lane >> 4;
    const int ll = lane & 15;
    const int jq0 = wv * 32;

    #pragma unroll
    for (int mr = 0; mr < 8; ++mr) {
        const int i0 = mr * 16 + lg * 4;
        float mi[4], di[4];
        #pragma unroll
        for (int r = 0; r < 4; ++r) { mi[r] = mloc[i0 + r]; di[r] = dloc[i0 + r]; }
        #pragma unroll
        for (int nt = 0; nt < 2; ++nt) {
            int j = jq0 + nt * 16 + ll;
            f4v e = eqk_mfma(Ktp, Qp, mr, j, lg, ll);
            float p0 = __expf(e[0] - mi[0]) * di[0];      // no diag mask in e_w
            float p1 = __expf(e[1] - mi[1]) * di[1];
            float p2 = __expf(e[2] - mi[2]) * di[2];
            float p3 = __expf(e[3] - mi[3]) * di[3];
            uint2 wd;
            wd.x = f2bf(p0) | ((unsigned int)f2bf(p1) << 16);
            wd.y = f2bf(p2) | ((unsigned int)f2bf(p3) << 16);
            int sidx = (j * 128 + i0) ^ ((j & 7) << 3);
            *(uint2*)&Pt[sidx] = wd;
        }
    }

    unsigned short* obase = ow + (size_t)bb * C_ * HW_ + (size_t)alpha * W_;

    for (int ch = 0; ch < 4; ++ch) {
        __syncthreads();
        const unsigned short* vsrc = base + (size_t)(64 + ch * 64) * HW_;
        #pragma unroll
        for (int f = t; f < 1024; f += 256) {
            int c = f >> 4, i0 = (f & 15) * 8;
            u8v v = *(const u8v*)(vsrc + (size_t)c * HW_ + i0);
            *(u8v*)&Vl[(c * 128 + i0) ^ ((c & 7) << 3)] = v;
        }
        __syncthreads();

        f4v acc[8];
        #pragma unroll
        for (int nt = 0; nt < 8; ++nt) acc[nt] = (f4v){0.f, 0.f, 0.f, 0.f};

        #pragma unroll
        for (int kk = 0; kk < 4; ++kk) {
            int crow = wv * 16 + ll;
            s8v afr = *(const s8v*)&Vl[(crow * 128 + kk * 32 + lg * 8) ^ ((crow & 7) << 3)];
            #pragma unroll
            for (int nt = 0; nt < 8; ++nt) {
                int j = nt * 16 + ll;
                s8v bfr = *(const s8v*)&Pt[(j * 128 + kk * 32 + lg * 8) ^ ((j & 7) << 3)];
                acc[nt] = __builtin_amdgcn_mfma_f32_16x16x32_bf16(afr, bfr, acc[nt], 0, 0, 0);
            }
        }
        #pragma unroll
        for (int nt = 0; nt < 8; ++nt) {
            int j = nt * 16 + ll;
            #pragma unroll
            for (int r = 0; r < 4; ++r) {
                int c = ch * 64 + wv * 16 + lg * 4 + r;
                obase[(size_t)c * HW_ + j] = f2bf(acc[nt][r]);
            }
        }
    }
}

// ------------------------------- K5: out = x + gamma*(ow + oh^T)  (fused epilogue)
__global__ __launch_bounds__(256) void k_combine(
    const unsigned short* __restrict__ oh_t, const unsigned short* __restrict__ ow,
    const float* __restrict__ x, const float* __restrict__ gamma_p,
    float* __restrict__ out, int b0)
{
    __shared__ float tile[32][33];
    const int bb = blockIdx.z;
    const int c = blockIdx.y;
    const int th = (blockIdx.x & 3) * 32;
    const int tw = (blockIdx.x >> 2) * 32;
    const float gamma = gamma_p[0];
    const unsigned short* src = oh_t + (size_t)bb * W_ * C_ * H_;
    #pragma unroll
    for (int r = 0; r < 4; ++r) {
        int wl = threadIdx.y * 4 + r;
        tile[wl][threadIdx.x] =
            bfu(src[((size_t)(tw + wl) * C_ + c) * H_ + th + threadIdx.x]);
    }
    __syncthreads();
    const size_t pbase = ((size_t)bb * C_ + c) * HW_;
    const size_t gbase = ((size_t)(b0 + bb) * C_ + c) * HW_;
    #pragma unroll
    for (int r = 0; r < 4; ++r) {
        int hl = threadIdx.y * 4 + r;
        size_t idx = (size_t)(th + hl) * W_ + tw + threadIdx.x;
        float owv = bfu(ow[pbase + idx]);
        out[gbase + idx] = x[gbase + idx] + gamma * (owv + tile[threadIdx.x][hl]);
    }
}

// ------------------------------------------------------------------- launcher
extern "C" void kernel_launch(void* const* d_in, const int* in_sizes, int n_in,
                              void* d_out, int out_size, void* d_ws, size_t ws_size,
                              hipStream_t stream)
{
    (void)in_sizes; (void)n_in; (void)out_size;
    const float* x  = (const float*)d_in[0];
    const float* wq = (const float*)d_in[1];
    const float* bq = (const float*)d_in[2];
    const float* wk = (const float*)d_in[3];
    const float* bk = (const float*)d_in[4];
    const float* wv = (const float*)d_in[5];
    const float* bv = (const float*)d_in[6];
    const float* gm = (const float*)d_in[7];
    float* out = (float*)d_out;

    const size_t e_qkv  = (size_t)OC_ * HW_;   // bf16 elements
    const size_t e_out  = (size_t)C_ * HW_;    // bf16 elements
    const size_t e_stat = (size_t)HW_;         // fp32 elements
    const size_t perb_bytes = (e_qkv * 2 + e_out * 2) * 2 + e_stat * 8 * 4;
    const size_t wb_bytes = (size_t)OC_ * C_ * 2;
    int nbcap = (int)((ws_size - wb_bytes) / perb_bytes);
    if (nbcap > 8) nbcap = 8;
    if (nbcap < 1) nbcap = 1;

    unsigned short* Wb    = (unsigned short*)d_ws;
    unsigned short* qkv   = Wb    + (size_t)OC_ * C_;
    unsigned short* qkv_t = qkv   + e_qkv * nbcap;
    unsigned short* oh    = qkv_t + e_qkv * nbcap;
    unsigned short* ow    = oh    + e_out * nbcap;
    float* mh  = (float*)(ow + e_out * nbcap);
    float* sh  = mh  + e_stat * nbcap;
    float* mw  = sh  + e_stat * nbcap;
    float* sw  = mw  + e_stat * nbcap;
    float* mc  = sw  + e_stat * nbcap;
    float* dv  = mc  + e_stat * nbcap;
    float* mct = dv  + e_stat * nbcap;
    float* dvt = mct + e_stat * nbcap;

    k_wconv<<<dim3(80), 256, 0, stream>>>(wq, wk, wv, Wb);

    for (int b0 = 0; b0 < 8; b0 += nbcap) {
        int nb = 8 - b0 < nbcap ? 8 - b0 : nbcap;
        k_qkv<<<dim3(HW_ / 128, 5, nb), 256, 0, stream>>>(
            x, Wb, bq, bk, bv, qkv, b0);
        k_transpose_qkv<<<dim3(16, OC_, nb), dim3(32, 8), 0, stream>>>(qkv, qkv_t);
        k_stats_h<<<dim3(W_, nb), 256, 0, stream>>>(qkv_t, mh, sh);
        k_stats_w<<<dim3(H_, nb), 256, 0, stream>>>(qkv, mw, sw);
        int nstat = nb * HW_;
        k_prep<<<dim3((nstat + 255) / 256), 256, 0, stream>>>(
            mh, sh, mw, sw, mc, dv, mct, dvt, nstat);
        k_outh<<<dim3(W_, nb), 256, 0, stream>>>(qkv_t, mct, dvt, oh);
        k_outw<<<dim3(H_, nb), 256, 0, stream>>>(qkv, mc, dv, ow);
        k_combine<<<dim3(16, C_, nb), dim3(32, 8), 0, stream>>>(
            oh, ow, x, gm, out, b0);
    }
}

// Round 10
// 304.782 us; speedup vs baseline: 1.3807x; 1.0125x over previous
//
#include <hip/hip_runtime.h>
#include <math.h>

#define C_   256
#define CQ_  32
#define H_   128
#define W_   128
#define HW_  (H_ * W_)
#define OC_  320   // 0..31 q, 32..63 k, 64..319 v

typedef __attribute__((ext_vector_type(8))) short  s8v;   // 8 bf16 (A/B frag)
typedef __attribute__((ext_vector_type(4))) float  f4v;   // 4 fp32 (C/D frag)
typedef __attribute__((ext_vector_type(8))) unsigned short u8v;
typedef __attribute__((ext_vector_type(4))) unsigned short u4v;

__device__ inline unsigned short f2bf(float f) {
    unsigned int u = __float_as_uint(f);
    unsigned int r = (u + 0x7fffu + ((u >> 16) & 1u)) >> 16;
    return (unsigned short)r;
}
__device__ inline float bfu(unsigned short u) {
    return __uint_as_float((unsigned int)u << 16);
}

// ------------------------------------------------ K0: W -> bf16 (320x256)
__global__ __launch_bounds__(256) void k_wconv(
    const float* __restrict__ wq, const float* __restrict__ wk,
    const float* __restrict__ wv, unsigned short* __restrict__ Wb)
{
    int idx4 = blockIdx.x * 256 + threadIdx.x;     // 20480 total
    int e = idx4 * 4;
    int oc = e >> 8, k = e & 255;
    const float* src;
    if (oc < 32)      src = wq + (size_t)oc * C_ + k;
    else if (oc < 64) src = wk + (size_t)(oc - 32) * C_ + k;
    else              src = wv + (size_t)(oc - 64) * C_ + k;
    float4 v = *(const float4*)src;
    u4v o;
    o[0] = f2bf(v.x); o[1] = f2bf(v.y); o[2] = f2bf(v.z); o[3] = f2bf(v.w);
    *(u4v*)(Wb + e) = o;
}

// ---------------------------------------------------------- K1: QKV MFMA GEMM
// qkv[bb][oc][n] = W[oc,:] @ x[b0+bb][:,n] + bias[oc]   (bf16 out)
// v4: grid (HW/128, 2, nb), block 256 (4 waves); wave tile 160oc x 32n (mr=10).
//     W staged per K-chunk (160x64, reg-prefetched); X packed-bf16 (R7 path).
//     40 MFMA per barrier-pair per wave (2.5x R7) — attacks issue-boundness.
__global__ __launch_bounds__(256) void k_qkv(
    const float* __restrict__ x, const unsigned short* __restrict__ Wb,
    const float* __restrict__ bq, const float* __restrict__ bk,
    const float* __restrict__ bv,
    unsigned short* __restrict__ qkv, int b0)
{
    __shared__ __align__(16) unsigned short Wl[160][72];   // 22.5 KB (pitch 36 dw ≡ 4 banks)
    __shared__ __align__(16) unsigned int   Xp[32 * 132];  // 16.9 KB packed k-pairs
    const int t = threadIdx.x;
    const int lane = t & 63;
    const int wave = t >> 6;
    const int n0 = blockIdx.x * 128;
    const int ocblk = blockIdx.y * 160;
    const int bb = blockIdx.z;
    const float* xb = x + (size_t)(b0 + bb) * C_ * HW_;

    const int lg = lane >> 4;      // 0..3
    const int ll = lane & 15;      // 0..15
    const int n_w = wave * 32;

    const int kp8 = t >> 5;          // 0..7
    const int n4  = (t & 31) * 4;    // 0..124
    const int wrow = t >> 3;         // 0..31 base row for W stage
    const int wcg  = (t & 7) * 8;    // col group (shorts)
    float4 ra[4], rb[4];
    u8v wreg[5];

    // prologue: issue X(0) and W(0) loads
    #pragma unroll
    for (int p = 0; p < 4; ++p) {
        int krow = (p * 8 + kp8) * 2;
        ra[p] = *(const float4*)(xb + (size_t)krow * HW_ + n0 + n4);
        rb[p] = *(const float4*)(xb + (size_t)(krow + 1) * HW_ + n0 + n4);
    }
    #pragma unroll
    for (int q = 0; q < 5; ++q)
        wreg[q] = *(const u8v*)(Wb + (size_t)(ocblk + wrow + q * 32) * C_ + wcg);

    f4v acc[10][2];
    #pragma unroll
    for (int mr = 0; mr < 10; ++mr)
        #pragma unroll
        for (int nr = 0; nr < 2; ++nr)
            acc[mr][nr] = (f4v){0.f, 0.f, 0.f, 0.f};

    #pragma unroll
    for (int kc = 0; kc < 4; ++kc) {
        __syncthreads();   // prev chunk's LDS reads done
        // write X pack (fp32 pair -> bf16 dword, round half-up)
        #pragma unroll
        for (int p = 0; p < 4; ++p) {
            uint4 d;
            const float* af  = (const float*)&ra[p];
            const float* bf_ = (const float*)&rb[p];
            #pragma unroll
            for (int i = 0; i < 4; ++i) {
                unsigned int lo = (__float_as_uint(af[i])  + 0x8000u) >> 16;
                unsigned int hi = (__float_as_uint(bf_[i]) + 0x8000u) & 0xffff0000u;
                ((unsigned int*)&d)[i] = hi | lo;
            }
            *(uint4*)&Xp[(p * 8 + kp8) * 132 + n4] = d;
        }
        // write W slice
        #pragma unroll
        for (int q = 0; q < 5; ++q)
            *(u8v*)&Wl[wrow + q * 32][wcg] = wreg[q];
        __syncthreads();   // Xp/Wl ready
        // prefetch next chunk (consumed next iter — latency hides under MFMA)
        if (kc < 3) {
            #pragma unroll
            for (int p = 0; p < 4; ++p) {
                int krow = (kc + 1) * 64 + (p * 8 + kp8) * 2;
                ra[p] = *(const float4*)(xb + (size_t)krow * HW_ + n0 + n4);
                rb[p] = *(const float4*)(xb + (size_t)(krow + 1) * HW_ + n0 + n4);
            }
            #pragma unroll
            for (int q = 0; q < 5; ++q)
                wreg[q] = *(const u8v*)(
                    Wb + (size_t)(ocblk + wrow + q * 32) * C_ + (kc + 1) * 64 + wcg);
        }
        #pragma unroll
        for (int ks = 0; ks < 2; ++ks) {
            // B fragments (shared across all mr)
            s8v bfr[2];
            #pragma unroll
            for (int nr = 0; nr < 2; ++nr) {
                int4 bd;
                #pragma unroll
                for (int e2 = 0; e2 < 4; ++e2)
                    ((int*)&bd)[e2] =
                        Xp[(ks * 16 + lg * 4 + e2) * 132 + n_w + nr * 16 + ll];
                bfr[nr] = *(s8v*)&bd;
            }
            #pragma unroll
            for (int mr = 0; mr < 10; ++mr) {
                s8v afr = *(const s8v*)&Wl[mr * 16 + ll][ks * 32 + lg * 8];
                #pragma unroll
                for (int nr = 0; nr < 2; ++nr)
                    acc[mr][nr] = __builtin_amdgcn_mfma_f32_16x16x32_bf16(
                        afr, bfr[nr], acc[mr][nr], 0, 0, 0);
            }
        }
    }

    #pragma unroll
    for (int mr = 0; mr < 10; ++mr) {
        float bias[4];
        #pragma unroll
        for (int r = 0; r < 4; ++r) {
            int oc = ocblk + mr * 16 + lg * 4 + r;
            if (oc < 32)      bias[r] = bq[oc];
            else if (oc < 64) bias[r] = bk[oc - 32];
            else              bias[r] = bv[oc - 64];
        }
        #pragma unroll
        for (int nr = 0; nr < 2; ++nr) {
            int n = n0 + n_w + nr * 16 + ll;
            #pragma unroll
            for (int r = 0; r < 4; ++r) {
                int oc = ocblk + mr * 16 + lg * 4 + r;
                qkv[((size_t)bb * OC_ + oc) * HW_ + n] = f2bf(acc[mr][nr][r] + bias[r]);
            }
        }
    }
}

// ------------------------------------------------- K1b: transpose to (b,w,oc,h)
__global__ __launch_bounds__(256) void k_transpose_qkv(
    const unsigned short* __restrict__ qkv, unsigned short* __restrict__ qkv_t)
{
    __shared__ unsigned short tile[32][34];
    const int bb = blockIdx.z;
    const int oc = blockIdx.y;
    const int th = (blockIdx.x & 3) * 32;
    const int tw = (blockIdx.x >> 2) * 32;
    const unsigned short* src = qkv + ((size_t)bb * OC_ + oc) * HW_;
    #pragma unroll
    for (int r = 0; r < 4; ++r) {
        int h = threadIdx.y * 4 + r;
        tile[h][threadIdx.x] = src[(size_t)(th + h) * W_ + tw + threadIdx.x];
    }
    __syncthreads();
    unsigned short* dst = qkv_t + (size_t)bb * W_ * OC_ * H_;
    #pragma unroll
    for (int r = 0; r < 4; ++r) {
        int wl = threadIdx.y * 4 + r;
        dst[((size_t)(tw + wl) * OC_ + oc) * H_ + th + threadIdx.x] = tile[threadIdx.x][wl];
    }
}

// ---------------------------------------------------------------- shared helpers
__device__ inline void stage_KQ(const unsigned short* base, int cstride,
                                unsigned int* Ktp, unsigned int* Qp, int t)
{
    {   // Ktp: 128 rows x 2 halves = 256 units
        int i = t & 127, half = t >> 7, c0 = half * 16;
        unsigned int kr[16];
        #pragma unroll
        for (int cc = 0; cc < 16; ++cc)
            kr[cc] = base[(size_t)(32 + c0 + cc) * cstride + i];
        uint4 d0, d1;
        #pragma unroll
        for (int e2 = 0; e2 < 4; ++e2)
            ((unsigned int*)&d0)[e2] = kr[2 * e2] | (kr[2 * e2 + 1] << 16);
        #pragma unroll
        for (int e2 = 0; e2 < 4; ++e2)
            ((unsigned int*)&d1)[e2] = kr[8 + 2 * e2] | (kr[9 + 2 * e2] << 16);
        *(uint4*)&Ktp[i * 20 + half * 8]     = d0;
        *(uint4*)&Ktp[i * 20 + half * 8 + 4] = d1;
    }
    {   // Qp: 16 c2 x 16 j-groups = 256 units
        int c2 = t >> 4, j8 = (t & 15) * 8;
        u8v qa = *(const u8v*)(base + (size_t)(2 * c2) * cstride + j8);
        u8v qb = *(const u8v*)(base + (size_t)(2 * c2 + 1) * cstride + j8);
        uint4 e0, e1;
        #pragma unroll
        for (int e = 0; e < 4; ++e)
            ((unsigned int*)&e0)[e] =
                (unsigned int)qa[e] | ((unsigned int)qb[e] << 16);
        #pragma unroll
        for (int e = 0; e < 4; ++e)
            ((unsigned int*)&e1)[e] =
                (unsigned int)qa[4 + e] | ((unsigned int)qb[4 + e] << 16);
        *(uint4*)&Qp[c2 * 132 + j8]     = e0;
        *(uint4*)&Qp[c2 * 132 + j8 + 4] = e1;
    }
}

__device__ inline f4v eqk_mfma(const unsigned int* Ktp, const unsigned int* Qp,
                               int mr, int j, int lg, int ll)
{
    s8v afr = *(const s8v*)&Ktp[(mr * 16 + ll) * 20 + lg * 4];
    int4 bd;
    #pragma unroll
    for (int e2 = 0; e2 < 4; ++e2)
        ((int*)&bd)[e2] = Qp[(lg * 4 + e2) * 132 + j];
    s8v bfr = *(s8v*)&bd;
    return __builtin_amdgcn_mfma_f32_16x16x32_bf16(
        afr, bfr, (f4v){0.f, 0.f, 0.f, 0.f}, 0, 0, 0);
}

// ----------------------------------------------- K2a: column (e_h) stats (MFMA)
__global__ __launch_bounds__(256) void k_stats_h(
    const unsigned short* __restrict__ qkv_t,
    float* __restrict__ mh, float* __restrict__ sh)
{
    __shared__ __align__(16) unsigned int Ktp[128 * 20];
    __shared__ __align__(16) unsigned int Qp[16 * 132];
    const int t = threadIdx.x;
    const int beta = blockIdx.x;
    const int bb = blockIdx.y;
    const unsigned short* base = qkv_t + ((size_t)bb * W_ + beta) * OC_ * H_;
    stage_KQ(base, H_, Ktp, Qp, t);
    __syncthreads();

    const int lane = t & 63;
    const int wv = t >> 6;
    const int lg = lane >> 4;
    const int ll = lane & 15;

    #pragma unroll
    for (int ml = 0; ml < 2; ++ml) {
        const int mr = wv * 2 + ml;
        const int i0 = mr * 16 + lg * 4;
        f4v ef[8];
        #pragma unroll
        for (int nt = 0; nt < 8; ++nt) {
            f4v e = eqk_mfma(Ktp, Qp, mr, nt * 16 + ll, lg, ll);
            int j = nt * 16 + ll;
            #pragma unroll
            for (int r = 0; r < 4; ++r)
                if (i0 + r == j) e[r] = -INFINITY;   // diag mask
            ef[nt] = e;
        }
        #pragma unroll
        for (int r = 0; r < 4; ++r) {
            float mm = -INFINITY;
            #pragma unroll
            for (int nt = 0; nt < 8; ++nt) mm = fmaxf(mm, ef[nt][r]);
            #pragma unroll
            for (int s = 1; s < 16; s <<= 1) mm = fmaxf(mm, __shfl_xor(mm, s));
            float ss = 0.f;
            #pragma unroll
            for (int nt = 0; nt < 8; ++nt) ss += __expf(ef[nt][r] - mm);
            #pragma unroll
            for (int s = 1; s < 16; s <<= 1) ss += __shfl_xor(ss, s);
            if (ll == 0) {
                int i = i0 + r;
                mh[((size_t)bb * H_ + i) * W_ + beta] = mm;
                sh[((size_t)bb * H_ + i) * W_ + beta] = ss;
            }
        }
    }
}

// -------------------------------------------------- K2b: row (e_w) stats (MFMA)
__global__ __launch_bounds__(256) void k_stats_w(
    const unsigned short* __restrict__ qkv,
    float* __restrict__ mw, float* __restrict__ sw)
{
    __shared__ __align__(16) unsigned int Ktp[128 * 20];
    __shared__ __align__(16) unsigned int Qp[16 * 132];
    const int t = threadIdx.x;
    const int alpha = blockIdx.x;
    const int bb = blockIdx.y;
    const unsigned short* base = qkv + (size_t)bb * OC_ * HW_ + (size_t)alpha * W_;
    stage_KQ(base, HW_, Ktp, Qp, t);
    __syncthreads();

    const int lane = t & 63;
    const int wv = t >> 6;
    const int lg = lane >> 4;
    const int ll = lane & 15;

    #pragma unroll
    for (int ml = 0; ml < 2; ++ml) {
        const int mr = wv * 2 + ml;
        const int i0 = mr * 16 + lg * 4;
        f4v ef[8];
        #pragma unroll
        for (int nt = 0; nt < 8; ++nt)
            ef[nt] = eqk_mfma(Ktp, Qp, mr, nt * 16 + ll, lg, ll);
        #pragma unroll
        for (int r = 0; r < 4; ++r) {
            float mm = -INFINITY;
            #pragma unroll
            for (int nt = 0; nt < 8; ++nt) mm = fmaxf(mm, ef[nt][r]);
            #pragma unroll
            for (int s = 1; s < 16; s <<= 1) mm = fmaxf(mm, __shfl_xor(mm, s));
            float ss = 0.f;
            #pragma unroll
            for (int nt = 0; nt < 8; ++nt) ss += __expf(ef[nt][r] - mm);
            #pragma unroll
            for (int s = 1; s < 16; s <<= 1) ss += __shfl_xor(ss, s);
            if (ll == 0) {
                int i = i0 + r;
                mw[((size_t)bb * H_ + alpha) * W_ + i] = mm;
                sw[((size_t)bb * H_ + alpha) * W_ + i] = ss;
            }
        }
    }
}

// ------------------------------- K2c: combine stats -> m_comb, d_inv (+transposed)
__global__ __launch_bounds__(256) void k_prep(
    const float* __restrict__ mh, const float* __restrict__ sh,
    const float* __restrict__ mw, const float* __restrict__ sw,
    float* __restrict__ mc, float* __restrict__ dv,
    float* __restrict__ mct, float* __restrict__ dvt, int n)
{
    int idx = blockIdx.x * 256 + threadIdx.x;
    if (idx >= n) return;
    float m1 = mh[idx], s1 = sh[idx], m2 = mw[idx], s2 = sw[idx];
    float m = fmaxf(m1, m2);
    float d = 1.f / (s1 * __expf(m1 - m) + s2 * __expf(m2 - m));
    mc[idx] = m; dv[idx] = d;
    int q = idx & (W_ - 1);
    int p = (idx >> 7) & (H_ - 1);
    int b = idx >> 14;
    size_t tid = ((size_t)b * W_ + q) * H_ + p;
    mct[tid] = m; dvt[tid] = d;
}

// -------------------------------------------------------------- K3: out_h (MFMA)
// v2: + T14 async V-stage (V(0) issued before P phase; V(ch+1) under PV MFMA)
__global__ __launch_bounds__(256) void k_outh(
    const unsigned short* __restrict__ qkv_t,
    const float* __restrict__ mct, const float* __restrict__ dvt,
    unsigned short* __restrict__ oh_t)
{
    __shared__ __align__(16) unsigned short Pt[128 * 128];   // swizzled, 32 KB
    __shared__ __align__(16) unsigned char  Ubuf[18688];     // Ktp+Qp | Vl
    __shared__ float mloc[128], dloc[128];
    unsigned int* Ktp = (unsigned int*)Ubuf;                 // [128][20]
    unsigned int* Qp  = (unsigned int*)(Ubuf + 10240);       // [16][132]
    unsigned short* Vl = (unsigned short*)Ubuf;              // [64][128] swizzled

    const int t = threadIdx.x;
    const int beta = blockIdx.x;
    const int bb = blockIdx.y;
    const unsigned short* base = qkv_t + ((size_t)bb * W_ + beta) * OC_ * H_;

    if (t < 128) {
        size_t sidx = ((size_t)bb * W_ + beta) * H_ + t;
        mloc[t] = mct[sidx];
        dloc[t] = dvt[sidx];
    }
    stage_KQ(base, H_, Ktp, Qp, t);

    // T14: issue V(0) global loads now — latency hidden by P phase below
    const int vc  = t >> 4;           // 0..15 (row block)
    const int vi0 = (t & 15) * 8;     // col
    u8v vreg[4];
    {
        const unsigned short* vsrc = base + (size_t)64 * H_;
        #pragma unroll
        for (int q = 0; q < 4; ++q)
            vreg[q] = *(const u8v*)(vsrc + (size_t)(vc + q * 16) * H_ + vi0);
    }
    __syncthreads();

    const int lane = t & 63;
    const int wv = t >> 6;
    const int lg = lane >> 4;
    const int ll = lane & 15;
    const int jq0 = wv * 32;

    // QK^T via MFMA + in-register softmax -> Pt (b64 writes, swizzle-compatible)
    #pragma unroll
    for (int mr = 0; mr < 8; ++mr) {
        const int i0 = mr * 16 + lg * 4;
        float mi[4], di[4];
        #pragma unroll
        for (int r = 0; r < 4; ++r) { mi[r] = mloc[i0 + r]; di[r] = dloc[i0 + r]; }
        #pragma unroll
        for (int nt = 0; nt < 2; ++nt) {
            int j = jq0 + nt * 16 + ll;
            f4v e = eqk_mfma(Ktp, Qp, mr, j, lg, ll);
            float p0 = (i0     == j) ? 0.f : __expf(e[0] - mi[0]) * di[0];
            float p1 = (i0 + 1 == j) ? 0.f : __expf(e[1] - mi[1]) * di[1];
            float p2 = (i0 + 2 == j) ? 0.f : __expf(e[2] - mi[2]) * di[2];
            float p3 = (i0 + 3 == j) ? 0.f : __expf(e[3] - mi[3]) * di[3];
            uint2 wd;
            wd.x = f2bf(p0) | ((unsigned int)f2bf(p1) << 16);
            wd.y = f2bf(p2) | ((unsigned int)f2bf(p3) << 16);
            int sidx = (j * 128 + i0) ^ ((j & 7) << 3);
            *(uint2*)&Pt[sidx] = wd;
        }
    }

    unsigned short* outbase = oh_t + ((size_t)bb * W_ + beta) * C_ * H_;

    for (int ch = 0; ch < 4; ++ch) {
        __syncthreads();   // Ktp/Qp (ch=0) or prev Vl reads done
        #pragma unroll
        for (int q = 0; q < 4; ++q) {
            int c = vc + q * 16;
            *(u8v*)&Vl[(c * 128 + vi0) ^ ((c & 7) << 3)] = vreg[q];
        }
        __syncthreads();
        if (ch < 3) {   // T14: next V chunk under this chunk's MFMA
            const unsigned short* vsrc = base + (size_t)(64 + (ch + 1) * 64) * H_;
            #pragma unroll
            for (int q = 0; q < 4; ++q)
                vreg[q] = *(const u8v*)(vsrc + (size_t)(vc + q * 16) * H_ + vi0);
        }

        f4v acc[8];
        #pragma unroll
        for (int nt = 0; nt < 8; ++nt) acc[nt] = (f4v){0.f, 0.f, 0.f, 0.f};

        #pragma unroll
        for (int kk = 0; kk < 4; ++kk) {
            int crow = wv * 16 + ll;
            s8v afr = *(const s8v*)&Vl[(crow * 128 + kk * 32 + lg * 8) ^ ((crow & 7) << 3)];
            #pragma unroll
            for (int nt = 0; nt < 8; ++nt) {
                int j = nt * 16 + ll;
                s8v bfr = *(const s8v*)&Pt[(j * 128 + kk * 32 + lg * 8) ^ ((j & 7) << 3)];
                acc[nt] = __builtin_amdgcn_mfma_f32_16x16x32_bf16(afr, bfr, acc[nt], 0, 0, 0);
            }
        }
        #pragma unroll
        for (int nt = 0; nt < 8; ++nt) {
            int j = nt * 16 + ll;
            #pragma unroll
            for (int r = 0; r < 4; ++r) {
                int c = ch * 64 + wv * 16 + lg * 4 + r;
                outbase[(size_t)c * H_ + j] = f2bf(acc[nt][r]);
            }
        }
    }
}

// -------------------------------------------------------------- K4: out_w (MFMA)
__global__ __launch_bounds__(256) void k_outw(
    const unsigned short* __restrict__ qkv,
    const float* __restrict__ mc, const float* __restrict__ dv_,
    unsigned short* __restrict__ ow)
{
    __shared__ __align__(16) unsigned short Pt[128 * 128];
    __shared__ __align__(16) unsigned char  Ubuf[18688];
    __shared__ float mloc[128], dloc[128];
    unsigned int* Ktp = (unsigned int*)Ubuf;
    unsigned int* Qp  = (unsigned int*)(Ubuf + 10240);
    unsigned short* Vl = (unsigned short*)Ubuf;

    const int t = threadIdx.x;
    const int alpha = blockIdx.x;
    const int bb = blockIdx.y;
    const unsigned short* base = qkv + (size_t)bb * OC_ * HW_ + (size_t)alpha * W_;

    if (t < 128) {
        size_t sidx = ((size_t)bb * H_ + alpha) * W_ + t;
        mloc[t] = mc[sidx];
        dloc[t] = dv_[sidx];
    }
    stage_KQ(base, HW_, Ktp, Qp, t);

    const int vc  = t >> 4;
    const int vi0 = (t & 15) * 8;
    u8v vreg[4];
    {
        const unsigned short* vsrc = base + (size_t)64 * HW_;
        #pragma unroll
        for (int q = 0; q < 4; ++q)
            vreg[q] = *(const u8v*)(vsrc + (size_t)(vc + q * 16) * HW_ + vi0);
    }
    __syncthreads();

    const int lane = t & 63;
    const int wv = t >> 6;
    const int lg = lane >> 4;
    const int ll = lane & 15;
    const int jq0 = wv * 32;

    #pragma unroll
    for (int mr = 0; mr < 8; ++mr) {
        const int i0 = mr * 16 + lg * 4;
        float mi[4], di[4];
        #pragma unroll
        for (int r = 0; r < 4; ++r) { mi[r] = mloc[i0 + r]; di[r] = dloc[i0 + r]; }
        #pragma unroll
        for (int nt = 0; nt < 2; ++nt) {
            int j = jq0 + nt * 16 + ll;
            f4v e = eqk_mfma(Ktp, Qp, mr, j, lg, ll);
            float p0 = __expf(e[0] - mi[0]) * di[0];      // no diag mask in e_w
            float p1 = __expf(e[1] - mi[1]) * di[1];
            float p2 = __expf(e[2] - mi[2]) * di[2];
            float p3 = __expf(e[3] - mi[3]) * di[3];
            uint2 wd;
            wd.x = f2bf(p0) | ((unsigned int)f2bf(p1) << 16);
            wd.y = f2bf(p2) | ((unsigned int)f2bf(p3) << 16);
            int sidx = (j * 128 + i0) ^ ((j & 7) << 3);
            *(uint2*)&Pt[sidx] = wd;
        }
    }

    unsigned short* obase = ow + (size_t)bb * C_ * HW_ + (size_t)alpha * W_;

    for (int ch = 0; ch < 4; ++ch) {
        __syncthreads();
        #pragma unroll
        for (int q = 0; q < 4; ++q) {
            int c = vc + q * 16;
            *(u8v*)&Vl[(c * 128 + vi0) ^ ((c & 7) << 3)] = vreg[q];
        }
        __syncthreads();
        if (ch < 3) {
            const unsigned short* vsrc = base + (size_t)(64 + (ch + 1) * 64) * HW_;
            #pragma unroll
            for (int q = 0; q < 4; ++q)
                vreg[q] = *(const u8v*)(vsrc + (size_t)(vc + q * 16) * HW_ + vi0);
        }

        f4v acc[8];
        #pragma unroll
        for (int nt = 0; nt < 8; ++nt) acc[nt] = (f4v){0.f, 0.f, 0.f, 0.f};

        #pragma unroll
        for (int kk = 0; kk < 4; ++kk) {
            int crow = wv * 16 + ll;
            s8v afr = *(const s8v*)&Vl[(crow * 128 + kk * 32 + lg * 8) ^ ((crow & 7) << 3)];
            #pragma unroll
            for (int nt = 0; nt < 8; ++nt) {
                int j = nt * 16 + ll;
                s8v bfr = *(const s8v*)&Pt[(j * 128 + kk * 32 + lg * 8) ^ ((j & 7) << 3)];
                acc[nt] = __builtin_amdgcn_mfma_f32_16x16x32_bf16(afr, bfr, acc[nt], 0, 0, 0);
            }
        }
        #pragma unroll
        for (int nt = 0; nt < 8; ++nt) {
            int j = nt * 16 + ll;
            #pragma unroll
            for (int r = 0; r < 4; ++r) {
                int c = ch * 64 + wv * 16 + lg * 4 + r;
                obase[(size_t)c * HW_ + j] = f2bf(acc[nt][r]);
            }
        }
    }
}

// ------------------------------- K5: out = x + gamma*(ow + oh^T)  (fused epilogue)
__global__ __launch_bounds__(256) void k_combine(
    const unsigned short* __restrict__ oh_t, const unsigned short* __restrict__ ow,
    const float* __restrict__ x, const float* __restrict__ gamma_p,
    float* __restrict__ out, int b0)
{
    __shared__ float tile[32][33];
    const int bb = blockIdx.z;
    const int c = blockIdx.y;
    const int th = (blockIdx.x & 3) * 32;
    const int tw = (blockIdx.x >> 2) * 32;
    const float gamma = gamma_p[0];
    const unsigned short* src = oh_t + (size_t)bb * W_ * C_ * H_;
    #pragma unroll
    for (int r = 0; r < 4; ++r) {
        int wl = threadIdx.y * 4 + r;
        tile[wl][threadIdx.x] =
            bfu(src[((size_t)(tw + wl) * C_ + c) * H_ + th + threadIdx.x]);
    }
    __syncthreads();
    const size_t pbase = ((size_t)bb * C_ + c) * HW_;
    const size_t gbase = ((size_t)(b0 + bb) * C_ + c) * HW_;
    #pragma unroll
    for (int r = 0; r < 4; ++r) {
        int hl = threadIdx.y * 4 + r;
        size_t idx = (size_t)(th + hl) * W_ + tw + threadIdx.x;
        float owv = bfu(ow[pbase + idx]);
        out[gbase + idx] = x[gbase + idx] + gamma * (owv + tile[threadIdx.x][hl]);
    }
}

// ------------------------------------------------------------------- launcher
extern "C" void kernel_launch(void* const* d_in, const int* in_sizes, int n_in,
                              void* d_out, int out_size, void* d_ws, size_t ws_size,
                              hipStream_t stream)
{
    (void)in_sizes; (void)n_in; (void)out_size;
    const float* x  = (const float*)d_in[0];
    const float* wq = (const float*)d_in[1];
    const float* bq = (const float*)d_in[2];
    const float* wk = (const float*)d_in[3];
    const float* bk = (const float*)d_in[4];
    const float* wv = (const float*)d_in[5];
    const float* bv = (const float*)d_in[6];
    const float* gm = (const float*)d_in[7];
    float* out = (float*)d_out;

    const size_t e_qkv  = (size_t)OC_ * HW_;   // bf16 elements
    const size_t e_out  = (size_t)C_ * HW_;    // bf16 elements
    const size_t e_stat = (size_t)HW_;         // fp32 elements
    const size_t perb_bytes = (e_qkv * 2 + e_out * 2) * 2 + e_stat * 8 * 4;
    const size_t wb_bytes = (size_t)OC_ * C_ * 2;
    int nbcap = (int)((ws_size - wb_bytes) / perb_bytes);
    if (nbcap > 8) nbcap = 8;
    if (nbcap < 1) nbcap = 1;

    unsigned short* Wb    = (unsigned short*)d_ws;
    unsigned short* qkv   = Wb    + (size_t)OC_ * C_;
    unsigned short* qkv_t = qkv   + e_qkv * nbcap;
    unsigned short* oh    = qkv_t + e_qkv * nbcap;
    unsigned short* ow    = oh    + e_out * nbcap;
    float* mh  = (float*)(ow + e_out * nbcap);
    float* sh  = mh  + e_stat * nbcap;
    float* mw  = sh  + e_stat * nbcap;
    float* sw  = mw  + e_stat * nbcap;
    float* mc  = sw  + e_stat * nbcap;
    float* dv  = mc  + e_stat * nbcap;
    float* mct = dv  + e_stat * nbcap;
    float* dvt = mct + e_stat * nbcap;

    k_wconv<<<dim3(80), 256, 0, stream>>>(wq, wk, wv, Wb);

    for (int b0 = 0; b0 < 8; b0 += nbcap) {
        int nb = 8 - b0 < nbcap ? 8 - b0 : nbcap;
        k_qkv<<<dim3(HW_ / 128, 2, nb), 256, 0, stream>>>(
            x, Wb, bq, bk, bv, qkv, b0);
        k_transpose_qkv<<<dim3(16, OC_, nb), dim3(32, 8), 0, stream>>>(qkv, qkv_t);
        k_stats_h<<<dim3(W_, nb), 256, 0, stream>>>(qkv_t, mh, sh);
        k_stats_w<<<dim3(H_, nb), 256, 0, stream>>>(qkv, mw, sw);
        int nstat = nb * HW_;
        k_prep<<<dim3((nstat + 255) / 256), 256, 0, stream>>>(
            mh, sh, mw, sw, mc, dv, mct, dvt, nstat);
        k_outh<<<dim3(W_, nb), 256, 0, stream>>>(qkv_t, mct, dvt, oh);
        k_outw<<<dim3(H_, nb), 256, 0, stream>>>(qkv, mc, dv, ow);
        k_combine<<<dim3(16, C_, nb), dim3(32, 8), 0, stream>>>(
            oh, ow, x, gm, out, b0);
    }
}

// Round 11
// 289.936 us; speedup vs baseline: 1.4514x; 1.0512x over previous
//
#include <hip/hip_runtime.h>
#include <math.h>

#define C_   256
#define CQ_  32
#define H_   128
#define W_   128
#define HW_  (H_ * W_)
#define OC_  320   // 0..31 q, 32..63 k, 64..319 v

typedef __attribute__((ext_vector_type(8))) short  s8v;   // 8 bf16 (A/B frag)
typedef __attribute__((ext_vector_type(4))) float  f4v;   // 4 fp32 (C/D frag)
typedef __attribute__((ext_vector_type(8))) unsigned short u8v;
typedef __attribute__((ext_vector_type(4))) unsigned short u4v;

__device__ inline unsigned short f2bf(float f) {
    unsigned int u = __float_as_uint(f);
    unsigned int r = (u + 0x7fffu + ((u >> 16) & 1u)) >> 16;
    return (unsigned short)r;
}
__device__ inline float bfu(unsigned short u) {
    return __uint_as_float((unsigned int)u << 16);
}

// ------------------------------------------------ K0: W -> bf16 (320x256)
__global__ __launch_bounds__(256) void k_wconv(
    const float* __restrict__ wq, const float* __restrict__ wk,
    const float* __restrict__ wv, unsigned short* __restrict__ Wb)
{
    int idx4 = blockIdx.x * 256 + threadIdx.x;     // 20480 total
    int e = idx4 * 4;
    int oc = e >> 8, k = e & 255;
    const float* src;
    if (oc < 32)      src = wq + (size_t)oc * C_ + k;
    else if (oc < 64) src = wk + (size_t)(oc - 32) * C_ + k;
    else              src = wv + (size_t)(oc - 64) * C_ + k;
    float4 v = *(const float4*)src;
    u4v o;
    o[0] = f2bf(v.x); o[1] = f2bf(v.y); o[2] = f2bf(v.z); o[3] = f2bf(v.w);
    *(u4v*)(Wb + e) = o;
}

// ---------------------------------------------------------- K1: QKV MFMA GEMM
// qkv[bb][oc][n] = W[oc,:] @ x[b0+bb][:,n] + bias[oc]   (bf16 out)
// v5: R7 geometry (64oc x 128n, grid.y=5) + TRUE double-buffer on Xp AND a
//     per-chunk W slice. ONE barrier per K-64 chunk; pack(k+1)/prefetch(k+2)
//     issue before the MFMA cluster so latency hides under compute.
__global__ __launch_bounds__(256) void k_qkv(
    const float* __restrict__ x, const unsigned short* __restrict__ Wb,
    const float* __restrict__ bq, const float* __restrict__ bk,
    const float* __restrict__ bv,
    unsigned short* __restrict__ qkv, int b0)
{
    __shared__ __align__(16) unsigned short Wl[2][64][72];   // 18.4 KB
    __shared__ __align__(16) unsigned int   Xp[2][32 * 132]; // 33.8 KB
    const int t = threadIdx.x;
    const int lane = t & 63;
    const int wave = t >> 6;
    const int n0 = blockIdx.x * 128;
    const int ocblk = blockIdx.y * 64;
    const int bb = blockIdx.z;
    const float* xb = x + (size_t)(b0 + bb) * C_ * HW_;

    const int lg = lane >> 4;      // 0..3
    const int ll = lane & 15;      // 0..15
    const int n_w = wave * 32;

    const int kp8 = t >> 5;          // 0..7
    const int n4  = (t & 31) * 4;    // 0..124
    const int wrow = t >> 3;         // 0..31
    const int wcg  = (t & 7) * 8;    // 0..56 (shorts)
    float4 ra[4], rb[4];
    u8v wreg[2];

    // ---- prologue: chunk 0 -> regs -> buf0; issue chunk 1 loads
    #pragma unroll
    for (int p = 0; p < 4; ++p) {
        int krow = (p * 8 + kp8) * 2;
        ra[p] = *(const float4*)(xb + (size_t)krow * HW_ + n0 + n4);
        rb[p] = *(const float4*)(xb + (size_t)(krow + 1) * HW_ + n0 + n4);
    }
    #pragma unroll
    for (int q = 0; q < 2; ++q)
        wreg[q] = *(const u8v*)(Wb + (size_t)(ocblk + wrow + q * 32) * C_ + wcg);

    #pragma unroll
    for (int p = 0; p < 4; ++p) {
        uint4 d;
        const float* af  = (const float*)&ra[p];
        const float* bf_ = (const float*)&rb[p];
        #pragma unroll
        for (int i = 0; i < 4; ++i) {
            unsigned int lo = (__float_as_uint(af[i])  + 0x8000u) >> 16;
            unsigned int hi = (__float_as_uint(bf_[i]) + 0x8000u) & 0xffff0000u;
            ((unsigned int*)&d)[i] = hi | lo;
        }
        *(uint4*)&Xp[0][(p * 8 + kp8) * 132 + n4] = d;
    }
    #pragma unroll
    for (int q = 0; q < 2; ++q)
        *(u8v*)&Wl[0][wrow + q * 32][wcg] = wreg[q];

    #pragma unroll
    for (int p = 0; p < 4; ++p) {
        int krow = 64 + (p * 8 + kp8) * 2;
        ra[p] = *(const float4*)(xb + (size_t)krow * HW_ + n0 + n4);
        rb[p] = *(const float4*)(xb + (size_t)(krow + 1) * HW_ + n0 + n4);
    }
    #pragma unroll
    for (int q = 0; q < 2; ++q)
        wreg[q] = *(const u8v*)(Wb + (size_t)(ocblk + wrow + q * 32) * C_ + 64 + wcg);

    f4v acc[4][2];
    #pragma unroll
    for (int mr = 0; mr < 4; ++mr)
        #pragma unroll
        for (int nr = 0; nr < 2; ++nr)
            acc[mr][nr] = (f4v){0.f, 0.f, 0.f, 0.f};

    __syncthreads();   // buf0 ready

    #pragma unroll
    for (int kc = 0; kc < 4; ++kc) {
        const int cur = kc & 1;
        // write buf[cur^1] from regs (chunk kc+1) — overlaps with MFMA below
        if (kc < 3) {
            #pragma unroll
            for (int p = 0; p < 4; ++p) {
                uint4 d;
                const float* af  = (const float*)&ra[p];
                const float* bf_ = (const float*)&rb[p];
                #pragma unroll
                for (int i = 0; i < 4; ++i) {
                    unsigned int lo = (__float_as_uint(af[i])  + 0x8000u) >> 16;
                    unsigned int hi = (__float_as_uint(bf_[i]) + 0x8000u) & 0xffff0000u;
                    ((unsigned int*)&d)[i] = hi | lo;
                }
                *(uint4*)&Xp[cur ^ 1][(p * 8 + kp8) * 132 + n4] = d;
            }
            #pragma unroll
            for (int q = 0; q < 2; ++q)
                *(u8v*)&Wl[cur ^ 1][wrow + q * 32][wcg] = wreg[q];
        }
        // issue chunk kc+2 global loads (consumed next iter)
        if (kc < 2) {
            #pragma unroll
            for (int p = 0; p < 4; ++p) {
                int krow = (kc + 2) * 64 + (p * 8 + kp8) * 2;
                ra[p] = *(const float4*)(xb + (size_t)krow * HW_ + n0 + n4);
                rb[p] = *(const float4*)(xb + (size_t)(krow + 1) * HW_ + n0 + n4);
            }
            #pragma unroll
            for (int q = 0; q < 2; ++q)
                wreg[q] = *(const u8v*)(
                    Wb + (size_t)(ocblk + wrow + q * 32) * C_ + (kc + 2) * 64 + wcg);
        }
        // MFMA on buf[cur]
        #pragma unroll
        for (int ks = 0; ks < 2; ++ks) {
            s8v afr[4];
            #pragma unroll
            for (int mr = 0; mr < 4; ++mr)
                afr[mr] = *(const s8v*)&Wl[cur][mr * 16 + ll][ks * 32 + lg * 8];
            #pragma unroll
            for (int nr = 0; nr < 2; ++nr) {
                int4 bd;
                #pragma unroll
                for (int e2 = 0; e2 < 4; ++e2)
                    ((int*)&bd)[e2] =
                        Xp[cur][(ks * 16 + lg * 4 + e2) * 132 + n_w + nr * 16 + ll];
                s8v bfr = *(s8v*)&bd;
                #pragma unroll
                for (int mr = 0; mr < 4; ++mr)
                    acc[mr][nr] = __builtin_amdgcn_mfma_f32_16x16x32_bf16(
                        afr[mr], bfr, acc[mr][nr], 0, 0, 0);
            }
        }
        __syncthreads();   // buf[cur^1] writes visible; buf[cur] reads done
    }

    #pragma unroll
    for (int mr = 0; mr < 4; ++mr) {
        float bias[4];
        #pragma unroll
        for (int r = 0; r < 4; ++r) {
            int oc = ocblk + mr * 16 + lg * 4 + r;
            if (oc < 32)      bias[r] = bq[oc];
            else if (oc < 64) bias[r] = bk[oc - 32];
            else              bias[r] = bv[oc - 64];
        }
        #pragma unroll
        for (int nr = 0; nr < 2; ++nr) {
            int n = n0 + n_w + nr * 16 + ll;
            #pragma unroll
            for (int r = 0; r < 4; ++r) {
                int oc = ocblk + mr * 16 + lg * 4 + r;
                qkv[((size_t)bb * OC_ + oc) * HW_ + n] = f2bf(acc[mr][nr][r] + bias[r]);
            }
        }
    }
}

// ------------------------------------------------- K1b: transpose to (b,w,oc,h)
__global__ __launch_bounds__(256) void k_transpose_qkv(
    const unsigned short* __restrict__ qkv, unsigned short* __restrict__ qkv_t)
{
    __shared__ unsigned short tile[32][34];
    const int bb = blockIdx.z;
    const int oc = blockIdx.y;
    const int th = (blockIdx.x & 3) * 32;
    const int tw = (blockIdx.x >> 2) * 32;
    const unsigned short* src = qkv + ((size_t)bb * OC_ + oc) * HW_;
    #pragma unroll
    for (int r = 0; r < 4; ++r) {
        int h = threadIdx.y * 4 + r;
        tile[h][threadIdx.x] = src[(size_t)(th + h) * W_ + tw + threadIdx.x];
    }
    __syncthreads();
    unsigned short* dst = qkv_t + (size_t)bb * W_ * OC_ * H_;
    #pragma unroll
    for (int r = 0; r < 4; ++r) {
        int wl = threadIdx.y * 4 + r;
        dst[((size_t)(tw + wl) * OC_ + oc) * H_ + th + threadIdx.x] = tile[threadIdx.x][wl];
    }
}

// ---------------------------------------------------------------- shared helpers
__device__ inline void stage_KQ(const unsigned short* base, int cstride,
                                unsigned int* Ktp, unsigned int* Qp, int t)
{
    {   // Ktp: 128 rows x 2 halves = 256 units
        int i = t & 127, half = t >> 7, c0 = half * 16;
        unsigned int kr[16];
        #pragma unroll
        for (int cc = 0; cc < 16; ++cc)
            kr[cc] = base[(size_t)(32 + c0 + cc) * cstride + i];
        uint4 d0, d1;
        #pragma unroll
        for (int e2 = 0; e2 < 4; ++e2)
            ((unsigned int*)&d0)[e2] = kr[2 * e2] | (kr[2 * e2 + 1] << 16);
        #pragma unroll
        for (int e2 = 0; e2 < 4; ++e2)
            ((unsigned int*)&d1)[e2] = kr[8 + 2 * e2] | (kr[9 + 2 * e2] << 16);
        *(uint4*)&Ktp[i * 20 + half * 8]     = d0;
        *(uint4*)&Ktp[i * 20 + half * 8 + 4] = d1;
    }
    {   // Qp: 16 c2 x 16 j-groups = 256 units
        int c2 = t >> 4, j8 = (t & 15) * 8;
        u8v qa = *(const u8v*)(base + (size_t)(2 * c2) * cstride + j8);
        u8v qb = *(const u8v*)(base + (size_t)(2 * c2 + 1) * cstride + j8);
        uint4 e0, e1;
        #pragma unroll
        for (int e = 0; e < 4; ++e)
            ((unsigned int*)&e0)[e] =
                (unsigned int)qa[e] | ((unsigned int)qb[e] << 16);
        #pragma unroll
        for (int e = 0; e < 4; ++e)
            ((unsigned int*)&e1)[e] =
                (unsigned int)qa[4 + e] | ((unsigned int)qb[4 + e] << 16);
        *(uint4*)&Qp[c2 * 132 + j8]     = e0;
        *(uint4*)&Qp[c2 * 132 + j8 + 4] = e1;
    }
}

__device__ inline f4v eqk_mfma(const unsigned int* Ktp, const unsigned int* Qp,
                               int mr, int j, int lg, int ll)
{
    s8v afr = *(const s8v*)&Ktp[(mr * 16 + ll) * 20 + lg * 4];
    int4 bd;
    #pragma unroll
    for (int e2 = 0; e2 < 4; ++e2)
        ((int*)&bd)[e2] = Qp[(lg * 4 + e2) * 132 + j];
    s8v bfr = *(s8v*)&bd;
    return __builtin_amdgcn_mfma_f32_16x16x32_bf16(
        afr, bfr, (f4v){0.f, 0.f, 0.f, 0.f}, 0, 0, 0);
}

// ----------------------------------------------- K2a: column (e_h) stats (MFMA)
__global__ __launch_bounds__(256) void k_stats_h(
    const unsigned short* __restrict__ qkv_t,
    float* __restrict__ mh, float* __restrict__ sh)
{
    __shared__ __align__(16) unsigned int Ktp[128 * 20];
    __shared__ __align__(16) unsigned int Qp[16 * 132];
    const int t = threadIdx.x;
    const int beta = blockIdx.x;
    const int bb = blockIdx.y;
    const unsigned short* base = qkv_t + ((size_t)bb * W_ + beta) * OC_ * H_;
    stage_KQ(base, H_, Ktp, Qp, t);
    __syncthreads();

    const int lane = t & 63;
    const int wv = t >> 6;
    const int lg = lane >> 4;
    const int ll = lane & 15;

    #pragma unroll
    for (int ml = 0; ml < 2; ++ml) {
        const int mr = wv * 2 + ml;
        const int i0 = mr * 16 + lg * 4;
        f4v ef[8];
        #pragma unroll
        for (int nt = 0; nt < 8; ++nt) {
            f4v e = eqk_mfma(Ktp, Qp, mr, nt * 16 + ll, lg, ll);
            int j = nt * 16 + ll;
            #pragma unroll
            for (int r = 0; r < 4; ++r)
                if (i0 + r == j) e[r] = -INFINITY;   // diag mask
            ef[nt] = e;
        }
        #pragma unroll
        for (int r = 0; r < 4; ++r) {
            float mm = -INFINITY;
            #pragma unroll
            for (int nt = 0; nt < 8; ++nt) mm = fmaxf(mm, ef[nt][r]);
            #pragma unroll
            for (int s = 1; s < 16; s <<= 1) mm = fmaxf(mm, __shfl_xor(mm, s));
            float ss = 0.f;
            #pragma unroll
            for (int nt = 0; nt < 8; ++nt) ss += __expf(ef[nt][r] - mm);
            #pragma unroll
            for (int s = 1; s < 16; s <<= 1) ss += __shfl_xor(ss, s);
            if (ll == 0) {
                int i = i0 + r;
                mh[((size_t)bb * H_ + i) * W_ + beta] = mm;
                sh[((size_t)bb * H_ + i) * W_ + beta] = ss;
            }
        }
    }
}

// -------------------------------------------------- K2b: row (e_w) stats (MFMA)
__global__ __launch_bounds__(256) void k_stats_w(
    const unsigned short* __restrict__ qkv,
    float* __restrict__ mw, float* __restrict__ sw)
{
    __shared__ __align__(16) unsigned int Ktp[128 * 20];
    __shared__ __align__(16) unsigned int Qp[16 * 132];
    const int t = threadIdx.x;
    const int alpha = blockIdx.x;
    const int bb = blockIdx.y;
    const unsigned short* base = qkv + (size_t)bb * OC_ * HW_ + (size_t)alpha * W_;
    stage_KQ(base, HW_, Ktp, Qp, t);
    __syncthreads();

    const int lane = t & 63;
    const int wv = t >> 6;
    const int lg = lane >> 4;
    const int ll = lane & 15;

    #pragma unroll
    for (int ml = 0; ml < 2; ++ml) {
        const int mr = wv * 2 + ml;
        const int i0 = mr * 16 + lg * 4;
        f4v ef[8];
        #pragma unroll
        for (int nt = 0; nt < 8; ++nt)
            ef[nt] = eqk_mfma(Ktp, Qp, mr, nt * 16 + ll, lg, ll);
        #pragma unroll
        for (int r = 0; r < 4; ++r) {
            float mm = -INFINITY;
            #pragma unroll
            for (int nt = 0; nt < 8; ++nt) mm = fmaxf(mm, ef[nt][r]);
            #pragma unroll
            for (int s = 1; s < 16; s <<= 1) mm = fmaxf(mm, __shfl_xor(mm, s));
            float ss = 0.f;
            #pragma unroll
            for (int nt = 0; nt < 8; ++nt) ss += __expf(ef[nt][r] - mm);
            #pragma unroll
            for (int s = 1; s < 16; s <<= 1) ss += __shfl_xor(ss, s);
            if (ll == 0) {
                int i = i0 + r;
                mw[((size_t)bb * H_ + alpha) * W_ + i] = mm;
                sw[((size_t)bb * H_ + alpha) * W_ + i] = ss;
            }
        }
    }
}

// ------------------------------- K2c: combine stats -> m_comb, d_inv (+transposed)
__global__ __launch_bounds__(256) void k_prep(
    const float* __restrict__ mh, const float* __restrict__ sh,
    const float* __restrict__ mw, const float* __restrict__ sw,
    float* __restrict__ mc, float* __restrict__ dv,
    float* __restrict__ mct, float* __restrict__ dvt, int n)
{
    int idx = blockIdx.x * 256 + threadIdx.x;
    if (idx >= n) return;
    float m1 = mh[idx], s1 = sh[idx], m2 = mw[idx], s2 = sw[idx];
    float m = fmaxf(m1, m2);
    float d = 1.f / (s1 * __expf(m1 - m) + s2 * __expf(m2 - m));
    mc[idx] = m; dv[idx] = d;
    int q = idx & (W_ - 1);
    int p = (idx >> 7) & (H_ - 1);
    int b = idx >> 14;
    size_t tid = ((size_t)b * W_ + q) * H_ + p;
    mct[tid] = m; dvt[tid] = d;
}

// -------------------------------------------------------------- K3: out_h (MFMA)
// v3: PV wave tile re-split to 32c x 64j (24 ds_read_b128 per 32 MFMA, was 36)
__global__ __launch_bounds__(256) void k_outh(
    const unsigned short* __restrict__ qkv_t,
    const float* __restrict__ mct, const float* __restrict__ dvt,
    unsigned short* __restrict__ oh_t)
{
    __shared__ __align__(16) unsigned short Pt[128 * 128];   // swizzled, 32 KB
    __shared__ __align__(16) unsigned char  Ubuf[18688];     // Ktp+Qp | Vl
    __shared__ float mloc[128], dloc[128];
    unsigned int* Ktp = (unsigned int*)Ubuf;                 // [128][20]
    unsigned int* Qp  = (unsigned int*)(Ubuf + 10240);       // [16][132]
    unsigned short* Vl = (unsigned short*)Ubuf;              // [64][128] swizzled

    const int t = threadIdx.x;
    const int beta = blockIdx.x;
    const int bb = blockIdx.y;
    const unsigned short* base = qkv_t + ((size_t)bb * W_ + beta) * OC_ * H_;

    if (t < 128) {
        size_t sidx = ((size_t)bb * W_ + beta) * H_ + t;
        mloc[t] = mct[sidx];
        dloc[t] = dvt[sidx];
    }
    stage_KQ(base, H_, Ktp, Qp, t);

    // T14: issue V(0) global loads now — latency hidden by P phase below
    const int vc  = t >> 4;           // 0..15 (row block)
    const int vi0 = (t & 15) * 8;     // col
    u8v vreg[4];
    {
        const unsigned short* vsrc = base + (size_t)64 * H_;
        #pragma unroll
        for (int q = 0; q < 4; ++q)
            vreg[q] = *(const u8v*)(vsrc + (size_t)(vc + q * 16) * H_ + vi0);
    }
    __syncthreads();

    const int lane = t & 63;
    const int wv = t >> 6;
    const int lg = lane >> 4;
    const int ll = lane & 15;
    const int jq0 = wv * 32;

    // QK^T via MFMA + in-register softmax -> Pt (b64 writes, swizzle-compatible)
    #pragma unroll
    for (int mr = 0; mr < 8; ++mr) {
        const int i0 = mr * 16 + lg * 4;
        float mi[4], di[4];
        #pragma unroll
        for (int r = 0; r < 4; ++r) { mi[r] = mloc[i0 + r]; di[r] = dloc[i0 + r]; }
        #pragma unroll
        for (int nt = 0; nt < 2; ++nt) {
            int j = jq0 + nt * 16 + ll;
            f4v e = eqk_mfma(Ktp, Qp, mr, j, lg, ll);
            float p0 = (i0     == j) ? 0.f : __expf(e[0] - mi[0]) * di[0];
            float p1 = (i0 + 1 == j) ? 0.f : __expf(e[1] - mi[1]) * di[1];
            float p2 = (i0 + 2 == j) ? 0.f : __expf(e[2] - mi[2]) * di[2];
            float p3 = (i0 + 3 == j) ? 0.f : __expf(e[3] - mi[3]) * di[3];
            uint2 wd;
            wd.x = f2bf(p0) | ((unsigned int)f2bf(p1) << 16);
            wd.y = f2bf(p2) | ((unsigned int)f2bf(p3) << 16);
            int sidx = (j * 128 + i0) ^ ((j & 7) << 3);
            *(uint2*)&Pt[sidx] = wd;
        }
    }

    unsigned short* outbase = oh_t + ((size_t)bb * W_ + beta) * C_ * H_;
    const int cw = (wv & 1) * 32;      // c base within chunk
    const int jw = (wv >> 1) * 64;     // j base

    for (int ch = 0; ch < 4; ++ch) {
        __syncthreads();   // Ktp/Qp (ch=0) or prev Vl reads done
        #pragma unroll
        for (int q = 0; q < 4; ++q) {
            int c = vc + q * 16;
            *(u8v*)&Vl[(c * 128 + vi0) ^ ((c & 7) << 3)] = vreg[q];
        }
        __syncthreads();
        if (ch < 3) {   // T14: next V chunk under this chunk's MFMA
            const unsigned short* vsrc = base + (size_t)(64 + (ch + 1) * 64) * H_;
            #pragma unroll
            for (int q = 0; q < 4; ++q)
                vreg[q] = *(const u8v*)(vsrc + (size_t)(vc + q * 16) * H_ + vi0);
        }

        f4v acc[2][4];
        #pragma unroll
        for (int cr = 0; cr < 2; ++cr)
            #pragma unroll
            for (int nt = 0; nt < 4; ++nt)
                acc[cr][nt] = (f4v){0.f, 0.f, 0.f, 0.f};

        #pragma unroll
        for (int kk = 0; kk < 4; ++kk) {
            s8v afr[2];
            #pragma unroll
            for (int cr = 0; cr < 2; ++cr) {
                int crow = cw + cr * 16 + ll;
                afr[cr] = *(const s8v*)&Vl[(crow * 128 + kk * 32 + lg * 8) ^ ((crow & 7) << 3)];
            }
            #pragma unroll
            for (int nt = 0; nt < 4; ++nt) {
                int j = jw + nt * 16 + ll;
                s8v bfr = *(const s8v*)&Pt[(j * 128 + kk * 32 + lg * 8) ^ ((j & 7) << 3)];
                acc[0][nt] = __builtin_amdgcn_mfma_f32_16x16x32_bf16(afr[0], bfr, acc[0][nt], 0, 0, 0);
                acc[1][nt] = __builtin_amdgcn_mfma_f32_16x16x32_bf16(afr[1], bfr, acc[1][nt], 0, 0, 0);
            }
        }
        #pragma unroll
        for (int cr = 0; cr < 2; ++cr)
            #pragma unroll
            for (int nt = 0; nt < 4; ++nt) {
                int j = jw + nt * 16 + ll;
                #pragma unroll
                for (int r = 0; r < 4; ++r) {
                    int c = ch * 64 + cw + cr * 16 + lg * 4 + r;
                    outbase[(size_t)c * H_ + j] = f2bf(acc[cr][nt][r]);
                }
            }
    }
}

// -------------------------------------------------------------- K4: out_w (MFMA)
__global__ __launch_bounds__(256) void k_outw(
    const unsigned short* __restrict__ qkv,
    const float* __restrict__ mc, const float* __restrict__ dv_,
    unsigned short* __restrict__ ow)
{
    __shared__ __align__(16) unsigned short Pt[128 * 128];
    __shared__ __align__(16) unsigned char  Ubuf[18688];
    __shared__ float mloc[128], dloc[128];
    unsigned int* Ktp = (unsigned int*)Ubuf;
    unsigned int* Qp  = (unsigned int*)(Ubuf + 10240);
    unsigned short* Vl = (unsigned short*)Ubuf;

    const int t = threadIdx.x;
    const int alpha = blockIdx.x;
    const int bb = blockIdx.y;
    const unsigned short* base = qkv + (size_t)bb * OC_ * HW_ + (size_t)alpha * W_;

    if (t < 128) {
        size_t sidx = ((size_t)bb * H_ + alpha) * W_ + t;
        mloc[t] = mc[sidx];
        dloc[t] = dv_[sidx];
    }
    stage_KQ(base, HW_, Ktp, Qp, t);

    const int vc  = t >> 4;
    const int vi0 = (t & 15) * 8;
    u8v vreg[4];
    {
        const unsigned short* vsrc = base + (size_t)64 * HW_;
        #pragma unroll
        for (int q = 0; q < 4; ++q)
            vreg[q] = *(const u8v*)(vsrc + (size_t)(vc + q * 16) * HW_ + vi0);
    }
    __syncthreads();

    const int lane = t & 63;
    const int wv = t >> 6;
    const int lg = lane >> 4;
    const int ll = lane & 15;
    const int jq0 = wv * 32;

    #pragma unroll
    for (int mr = 0; mr < 8; ++mr) {
        const int i0 = mr * 16 + lg * 4;
        float mi[4], di[4];
        #pragma unroll
        for (int r = 0; r < 4; ++r) { mi[r] = mloc[i0 + r]; di[r] = dloc[i0 + r]; }
        #pragma unroll
        for (int nt = 0; nt < 2; ++nt) {
            int j = jq0 + nt * 16 + ll;
            f4v e = eqk_mfma(Ktp, Qp, mr, j, lg, ll);
            float p0 = __expf(e[0] - mi[0]) * di[0];      // no diag mask in e_w
            float p1 = __expf(e[1] - mi[1]) * di[1];
            float p2 = __expf(e[2] - mi[2]) * di[2];
            float p3 = __expf(e[3] - mi[3]) * di[3];
            uint2 wd;
            wd.x = f2bf(p0) | ((unsigned int)f2bf(p1) << 16);
            wd.y = f2bf(p2) | ((unsigned int)f2bf(p3) << 16);
            int sidx = (j * 128 + i0) ^ ((j & 7) << 3);
            *(uint2*)&Pt[sidx] = wd;
        }
    }

    unsigned short* obase = ow + (size_t)bb * C_ * HW_ + (size_t)alpha * W_;
    const int cw = (wv & 1) * 32;
    const int jw = (wv >> 1) * 64;

    for (int ch = 0; ch < 4; ++ch) {
        __syncthreads();
        #pragma unroll
        for (int q = 0; q < 4; ++q) {
            int c = vc + q * 16;
            *(u8v*)&Vl[(c * 128 + vi0) ^ ((c & 7) << 3)] = vreg[q];
        }
        __syncthreads();
        if (ch < 3) {
            const unsigned short* vsrc = base + (size_t)(64 + (ch + 1) * 64) * HW_;
            #pragma unroll
            for (int q = 0; q < 4; ++q)
                vreg[q] = *(const u8v*)(vsrc + (size_t)(vc + q * 16) * HW_ + vi0);
        }

        f4v acc[2][4];
        #pragma unroll
        for (int cr = 0; cr < 2; ++cr)
            #pragma unroll
            for (int nt = 0; nt < 4; ++nt)
                acc[cr][nt] = (f4v){0.f, 0.f, 0.f, 0.f};

        #pragma unroll
        for (int kk = 0; kk < 4; ++kk) {
            s8v afr[2];
            #pragma unroll
            for (int cr = 0; cr < 2; ++cr) {
                int crow = cw + cr * 16 + ll;
                afr[cr] = *(const s8v*)&Vl[(crow * 128 + kk * 32 + lg * 8) ^ ((crow & 7) << 3)];
            }
            #pragma unroll
            for (int nt = 0; nt < 4; ++nt) {
                int j = jw + nt * 16 + ll;
                s8v bfr = *(const s8v*)&Pt[(j * 128 + kk * 32 + lg * 8) ^ ((j & 7) << 3)];
                acc[0][nt] = __builtin_amdgcn_mfma_f32_16x16x32_bf16(afr[0], bfr, acc[0][nt], 0, 0, 0);
                acc[1][nt] = __builtin_amdgcn_mfma_f32_16x16x32_bf16(afr[1], bfr, acc[1][nt], 0, 0, 0);
            }
        }
        #pragma unroll
        for (int cr = 0; cr < 2; ++cr)
            #pragma unroll
            for (int nt = 0; nt < 4; ++nt) {
                int j = jw + nt * 16 + ll;
                #pragma unroll
                for (int r = 0; r < 4; ++r) {
                    int c = ch * 64 + cw + cr * 16 + lg * 4 + r;
                    obase[(size_t)c * HW_ + j] = f2bf(acc[cr][nt][r]);
                }
            }
    }
}

// ------------------------------- K5: out = x + gamma*(ow + oh^T)  (fused epilogue)
__global__ __launch_bounds__(256) void k_combine(
    const unsigned short* __restrict__ oh_t, const unsigned short* __restrict__ ow,
    const float* __restrict__ x, const float* __restrict__ gamma_p,
    float* __restrict__ out, int b0)
{
    __shared__ float tile[32][33];
    const int bb = blockIdx.z;
    const int c = blockIdx.y;
    const int th = (blockIdx.x & 3) * 32;
    const int tw = (blockIdx.x >> 2) * 32;
    const float gamma = gamma_p[0];
    const unsigned short* src = oh_t + (size_t)bb * W_ * C_ * H_;
    #pragma unroll
    for (int r = 0; r < 4; ++r) {
        int wl = threadIdx.y * 4 + r;
        tile[wl][threadIdx.x] =
            bfu(src[((size_t)(tw + wl) * C_ + c) * H_ + th + threadIdx.x]);
    }
    __syncthreads();
    const size_t pbase = ((size_t)bb * C_ + c) * HW_;
    const size_t gbase = ((size_t)(b0 + bb) * C_ + c) * HW_;
    #pragma unroll
    for (int r = 0; r < 4; ++r) {
        int hl = threadIdx.y * 4 + r;
        size_t idx = (size_t)(th + hl) * W_ + tw + threadIdx.x;
        float owv = bfu(ow[pbase + idx]);
        out[gbase + idx] = x[gbase + idx] + gamma * (owv + tile[threadIdx.x][hl]);
    }
}

// ------------------------------------------------------------------- launcher
extern "C" void kernel_launch(void* const* d_in, const int* in_sizes, int n_in,
                              void* d_out, int out_size, void* d_ws, size_t ws_size,
                              hipStream_t stream)
{
    (void)in_sizes; (void)n_in; (void)out_size;
    const float* x  = (const float*)d_in[0];
    const float* wq = (const float*)d_in[1];
    const float* bq = (const float*)d_in[2];
    const float* wk = (const float*)d_in[3];
    const float* bk = (const float*)d_in[4];
    const float* wv = (const float*)d_in[5];
    const float* bv = (const float*)d_in[6];
    const float* gm = (const float*)d_in[7];
    float* out = (float*)d_out;

    const size_t e_qkv  = (size_t)OC_ * HW_;   // bf16 elements
    const size_t e_out  = (size_t)C_ * HW_;    // bf16 elements
    const size_t e_stat = (size_t)HW_;         // fp32 elements
    const size_t perb_bytes = (e_qkv * 2 + e_out * 2) * 2 + e_stat * 8 * 4;
    const size_t wb_bytes = (size_t)OC_ * C_ * 2;
    int nbcap = (int)((ws_size - wb_bytes) / perb_bytes);
    if (nbcap > 8) nbcap = 8;
    if (nbcap < 1) nbcap = 1;

    unsigned short* Wb    = (unsigned short*)d_ws;
    unsigned short* qkv   = Wb    + (size_t)OC_ * C_;
    unsigned short* qkv_t = qkv   + e_qkv * nbcap;
    unsigned short* oh    = qkv_t + e_qkv * nbcap;
    unsigned short* ow    = oh    + e_out * nbcap;
    float* mh  = (float*)(ow + e_out * nbcap);
    float* sh  = mh  + e_stat * nbcap;
    float* mw  = sh  + e_stat * nbcap;
    float* sw  = mw  + e_stat * nbcap;
    float* mc  = sw  + e_stat * nbcap;
    float* dv  = mc  + e_stat * nbcap;
    float* mct = dv  + e_stat * nbcap;
    float* dvt = mct + e_stat * nbcap;

    k_wconv<<<dim3(80), 256, 0, stream>>>(wq, wk, wv, Wb);

    for (int b0 = 0; b0 < 8; b0 += nbcap) {
        int nb = 8 - b0 < nbcap ? 8 - b0 : nbcap;
        k_qkv<<<dim3(HW_ / 128, 5, nb), 256, 0, stream>>>(
            x, Wb, bq, bk, bv, qkv, b0);
        k_transpose_qkv<<<dim3(16, OC_, nb), dim3(32, 8), 0, stream>>>(qkv, qkv_t);
        k_stats_h<<<dim3(W_, nb), 256, 0, stream>>>(qkv_t, mh, sh);
        k_stats_w<<<dim3(H_, nb), 256, 0, stream>>>(qkv, mw, sw);
        int nstat = nb * HW_;
        k_prep<<<dim3((nstat + 255) / 256), 256, 0, stream>>>(
            mh, sh, mw, sw, mc, dv, mct, dvt, nstat);
        k_outh<<<dim3(W_, nb), 256, 0, stream>>>(qkv_t, mct, dvt, oh);
        k_outw<<<dim3(H_, nb), 256, 0, stream>>>(qkv, mc, dv, ow);
        k_combine<<<dim3(16, C_, nb), dim3(32, 8), 0, stream>>>(
            oh, ow, x, gm, out, b0);
    }
}